// Round 8
// baseline (1046.460 us; speedup 1.0000x reference)
//
#include <hip/hip_runtime.h>
#include <math.h>

#define NB 8
#define NN 1024
#define NK 8
#define ND 256
#define ND2 512
#define NBK 64
#define EPSA 1e-8f
#define LNEPS 1e-5f
#define GSTEP (2.0f/31.0f)

using short8 = __attribute__((ext_vector_type(8))) short;
using short4v = __attribute__((ext_vector_type(4))) short;
using floatx4 = __attribute__((ext_vector_type(4))) float;

__device__ __forceinline__ short f2bf(float f) {
  unsigned u = __builtin_bit_cast(unsigned, f);
  u += 0x7fffu + ((u >> 16) & 1u);
  return (short)(u >> 16);
}
__device__ __forceinline__ float bf2f(short s) {
  unsigned u = ((unsigned)(unsigned short)s) << 16;
  return __builtin_bit_cast(float, u);
}

// ---------------- all weight conversions in one launch ----------------
// [0,131072) w1T[n][k]=w1[k][n]; [131072,262144) w2T[n][k]=w2[k][n];
// [262144,327680) wkT; [327680,393216) wvT; [393216,589824) wihB direct bf16;
// [589824,786432) whhB direct; [786432,851968) wqT[n][k]=wq[k][n];
// [851968,983040) w2B direct bf16 of ge_w2 [512][256]
__global__ __launch_bounds__(256) void k_cvt_all(
    const float* __restrict__ w1, const float* __restrict__ w2,
    const float* __restrict__ wk, const float* __restrict__ wv,
    const float* __restrict__ wih, const float* __restrict__ whh,
    const float* __restrict__ wq,
    short* __restrict__ w1T, short* __restrict__ w2T,
    short* __restrict__ wkT, short* __restrict__ wvT,
    short* __restrict__ wihB, short* __restrict__ whhB,
    short* __restrict__ wqT, short* __restrict__ w2B) {
  const int idx = blockIdx.x * 256 + threadIdx.x;
  if (idx < 131072) {
    const int n = idx >> 8, k = idx & 255;
    w1T[idx] = f2bf(w1[(size_t)k * 512 + n]);
  } else if (idx < 262144) {
    const int i = idx - 131072;
    const int n = i >> 9, k = i & 511;
    w2T[i] = f2bf(w2[(size_t)k * 256 + n]);
  } else if (idx < 327680) {
    const int i = idx - 262144;
    const int n = i >> 8, k = i & 255;
    wkT[i] = f2bf(wk[(size_t)k * 256 + n]);
  } else if (idx < 393216) {
    const int i = idx - 327680;
    const int n = i >> 8, k = i & 255;
    wvT[i] = f2bf(wv[(size_t)k * 256 + n]);
  } else if (idx < 589824) {
    const int i = idx - 393216;
    wihB[i] = f2bf(wih[i]);
  } else if (idx < 786432) {
    const int i = idx - 589824;
    whhB[i] = f2bf(whh[i]);
  } else if (idx < 851968) {
    const int i = idx - 786432;
    const int n = i >> 8, k = i & 255;
    wqT[i] = f2bf(wq[(size_t)k * 256 + n]);
  } else {
    const int i = idx - 851968;
    w2B[i] = f2bf(w2[i]);
  }
}

// ---------------- k/v projection via bf16 MFMA (LN stats inline) ----------------
__global__ __launch_bounds__(256, 2) void k_gemm_kv_mfma(
    const float* __restrict__ inp,
    const float* __restrict__ nig, const float* __restrict__ nib,
    const short* __restrict__ wkT, const short* __restrict__ wvT,
    float* __restrict__ kout, float* __restrict__ vout) {
  __shared__ __align__(16) short tln[64 * 264];
  const short* __restrict__ WT = blockIdx.z ? wvT : wkT;
  float* __restrict__ out = blockIdx.z ? vout : kout;
  const int row0 = blockIdx.x * 64;
  const int t = threadIdx.x;
  const int wave = t >> 6, lane = t & 63, l15 = lane & 15, quad = lane >> 4;
  {
    const int r = t >> 2, sub = t & 3;
    const float* xr = inp + (size_t)(row0 + r) * ND;
    float tv[64];
    float sum = 0.f, ssq = 0.f;
#pragma unroll
    for (int ii = 0; ii < 16; ii++) {
      const int d = sub * 4 + ii * 16;
      const float4 xv = *(const float4*)(xr + d);
      tv[ii * 4 + 0] = xv.x; sum += xv.x; ssq += xv.x * xv.x;
      tv[ii * 4 + 1] = xv.y; sum += xv.y; ssq += xv.y * xv.y;
      tv[ii * 4 + 2] = xv.z; sum += xv.z; ssq += xv.z * xv.z;
      tv[ii * 4 + 3] = xv.w; sum += xv.w; ssq += xv.w * xv.w;
    }
    sum += __shfl_xor(sum, 1); ssq += __shfl_xor(ssq, 1);
    sum += __shfl_xor(sum, 2); ssq += __shfl_xor(ssq, 2);
    const float mean = sum * (1.0f / ND);
    const float var = ssq * (1.0f / ND) - mean * mean;
    const float rstd = rsqrtf(var + LNEPS);
#pragma unroll
    for (int ii = 0; ii < 16; ii++) {
      const int d = sub * 4 + ii * 16;
      const float4 gg = *(const float4*)(nig + d);
      const float4 bb = *(const float4*)(nib + d);
      short4v pk;
      pk.x = f2bf((tv[ii * 4 + 0] - mean) * rstd * gg.x + bb.x);
      pk.y = f2bf((tv[ii * 4 + 1] - mean) * rstd * gg.y + bb.y);
      pk.z = f2bf((tv[ii * 4 + 2] - mean) * rstd * gg.z + bb.z);
      pk.w = f2bf((tv[ii * 4 + 3] - mean) * rstd * gg.w + bb.w);
      *(short4v*)&tln[r * 264 + d] = pk;
    }
  }
  __syncthreads();
  floatx4 acc[4][4];
#pragma unroll
  for (int mt = 0; mt < 4; mt++)
#pragma unroll
    for (int nt = 0; nt < 4; nt++) acc[mt][nt] = (floatx4){0.f, 0.f, 0.f, 0.f};
  const short* wp = WT + ((size_t)(wave * 64 + l15)) * 256 + quad * 8;
#pragma unroll
  for (int kk = 0; kk < 8; kk++) {
    short8 af[4];
#pragma unroll
    for (int mt = 0; mt < 4; mt++)
      af[mt] = *(const short8*)&tln[(mt * 16 + l15) * 264 + kk * 32 + quad * 8];
    short8 bf[4];
#pragma unroll
    for (int nt = 0; nt < 4; nt++)
      bf[nt] = *(const short8*)(wp + nt * 16 * 256 + kk * 32);
#pragma unroll
    for (int mt = 0; mt < 4; mt++)
#pragma unroll
      for (int nt = 0; nt < 4; nt++)
        acc[mt][nt] = __builtin_amdgcn_mfma_f32_16x16x32_bf16(af[mt], bf[nt], acc[mt][nt], 0, 0, 0);
  }
#pragma unroll
  for (int mt = 0; mt < 4; mt++)
#pragma unroll
    for (int nt = 0; nt < 4; nt++)
#pragma unroll
      for (int j = 0; j < 4; j++)
        out[(size_t)(row0 + mt * 16 + quad * 4 + j) * ND + wave * 64 + nt * 16 + l15] = acc[mt][nt][j];
}

// ---------------- fused grid_enc pass: GEMM1 only (W2 folded out) ----------------
#define LDA 264

__global__ __launch_bounds__(256, 3) void k_fused_mfma(
    const float* __restrict__ kv,
    const float* __restrict__ pos, const float* __restrict__ scl,
    const float* __restrict__ gpw, const float* __restrict__ gpb,
    const float* __restrict__ lng, const float* __restrict__ lnb,
    const short* __restrict__ w1T, const float* __restrict__ b1,
    const float* __restrict__ w2q, float* __restrict__ dots,
    const float* __restrict__ attn0, const float* __restrict__ stage,
    float* __restrict__ ph, const int mode) {
  __shared__ __align__(16) short tln[64 * LDA];  // 33 KB; dred aliases after barrier

  const int bk = blockIdx.y;
  const int n0 = blockIdx.x * 64;
  const int b = bk >> 3;
  const int t = threadIdx.x;
  const int wave = t >> 6;
  const int lane = t & 63;
  const int l15 = lane & 15;
  const int quad = lane >> 4;

  // ---- Phase A: tln = LN(kv + rel_enc) -> bf16 LDS (64 rows, 4 thr/row) ----
  {
    const float p0 = pos[bk * 2 + 0], p1 = pos[bk * 2 + 1];
    const float s0i = 1.0f / (scl[bk * 2 + 0] * 5.0f);
    const float s1i = 1.0f / (scl[bk * 2 + 1] * 5.0f);
    const int r = t >> 2;
    const int sub = t & 3;
    const int n = n0 + r;
    const float gx = -1.0f + GSTEP * (float)(n >> 5);
    const float gy = -1.0f + GSTEP * (float)(n & 31);
    const float rg0 = (gx - p0) * s0i;
    const float rg1 = (gy - p1) * s1i;
    const float* kvrow = kv + (size_t)(b * NN + n) * ND;
    float tv[64];
    float sum = 0.f, ssq = 0.f;
#pragma unroll
    for (int ii = 0; ii < 16; ii++) {
      const int d = sub * 4 + ii * 16;
      const float4 kv4 = *(const float4*)(kvrow + d);
      const float4 wa = *(const float4*)(gpw + d);
      const float4 wb = *(const float4*)(gpw + ND + d);
      const float4 pb = *(const float4*)(gpb + d);
      float v0 = kv4.x + rg0 * wa.x + rg1 * wb.x + pb.x;
      float v1 = kv4.y + rg0 * wa.y + rg1 * wb.y + pb.y;
      float v2 = kv4.z + rg0 * wa.z + rg1 * wb.z + pb.z;
      float v3 = kv4.w + rg0 * wa.w + rg1 * wb.w + pb.w;
      tv[ii * 4 + 0] = v0; sum += v0; ssq += v0 * v0;
      tv[ii * 4 + 1] = v1; sum += v1; ssq += v1 * v1;
      tv[ii * 4 + 2] = v2; sum += v2; ssq += v2 * v2;
      tv[ii * 4 + 3] = v3; sum += v3; ssq += v3 * v3;
    }
    sum += __shfl_xor(sum, 1); ssq += __shfl_xor(ssq, 1);
    sum += __shfl_xor(sum, 2); ssq += __shfl_xor(ssq, 2);
    const float mean = sum * (1.0f / ND);
    const float var = ssq * (1.0f / ND) - mean * mean;
    const float rstd = rsqrtf(var + LNEPS);
#pragma unroll
    for (int ii = 0; ii < 16; ii++) {
      const int d = sub * 4 + ii * 16;
      const float4 gg = *(const float4*)(lng + d);
      const float4 bb = *(const float4*)(lnb + d);
      short4v pk;
      pk.x = f2bf((tv[ii * 4 + 0] - mean) * rstd * gg.x + bb.x);
      pk.y = f2bf((tv[ii * 4 + 1] - mean) * rstd * gg.y + bb.y);
      pk.z = f2bf((tv[ii * 4 + 2] - mean) * rstd * gg.z + bb.z);
      pk.w = f2bf((tv[ii * 4 + 3] - mean) * rstd * gg.w + bb.w);
      *(short4v*)&tln[r * LDA + d] = pk;
    }
  }
  __syncthreads();

  // ---- GEMM1: h1 = tln @ W1T^T (relu+bias in epilogue). Wave owns 128 cols. ----
  floatx4 acc1[4][8];
#pragma unroll
  for (int mt = 0; mt < 4; mt++)
#pragma unroll
    for (int nt = 0; nt < 8; nt++) acc1[mt][nt] = (floatx4){0.f, 0.f, 0.f, 0.f};

  const short* w1p = w1T + ((size_t)(wave * 128 + l15)) * 256 + quad * 8;
#pragma unroll
  for (int kk = 0; kk < 8; kk++) {
    short8 af[4];
#pragma unroll
    for (int mt = 0; mt < 4; mt++)
      af[mt] = *(const short8*)&tln[(mt * 16 + l15) * LDA + kk * 32 + quad * 8];
    short8 bf[8];
#pragma unroll
    for (int nt = 0; nt < 8; nt++)
      bf[nt] = *(const short8*)(w1p + nt * 16 * 256 + kk * 32);
#pragma unroll
    for (int mt = 0; mt < 4; mt++)
#pragma unroll
      for (int nt = 0; nt < 8; nt++)
        acc1[mt][nt] = __builtin_amdgcn_mfma_f32_16x16x32_bf16(af[mt], bf[nt], acc1[mt][nt], 0, 0, 0);
  }

  float b1v[8];
#pragma unroll
  for (int nt = 0; nt < 8; nt++) b1v[nt] = b1[wave * 128 + nt * 16 + l15];

  if (mode == 0) {
    float w2qv[8];
#pragma unroll
    for (int nt = 0; nt < 8; nt++) w2qv[nt] = w2q[bk * 512 + wave * 128 + nt * 16 + l15];
    const float qb2 = stage[bk * 8 + 5];
    __syncthreads();  // all tln reads done; alias as dred
    float* dred = (float*)tln;
#pragma unroll
    for (int mt = 0; mt < 4; mt++)
#pragma unroll
      for (int j = 0; j < 4; j++) {
        float p = 0.f;
#pragma unroll
        for (int nt = 0; nt < 8; nt++)
          p = fmaf(fmaxf(acc1[mt][nt][j] + b1v[nt], 0.f), w2qv[nt], p);
        p += __shfl_xor(p, 1); p += __shfl_xor(p, 2);
        p += __shfl_xor(p, 4); p += __shfl_xor(p, 8);
        if (l15 == 0) dred[wave * 64 + mt * 16 + quad * 4 + j] = p;
      }
    __syncthreads();
    if (t < 64) {
      const float s = dred[t] + dred[64 + t] + dred[128 + t] + dred[192 + t];
      dots[bk * NN + n0 + t] = (s + qb2) * 0.0625f;
    }
  } else {
    const float dn = 1.0f / (stage[bk * 8 + 0] + (float)NN * EPSA);
    float aw[4][4];
#pragma unroll
    for (int mt = 0; mt < 4; mt++)
#pragma unroll
      for (int j = 0; j < 4; j++)
        aw[mt][j] = (attn0[bk * NN + n0 + mt * 16 + quad * 4 + j] + EPSA) * dn;
#pragma unroll
    for (int nt = 0; nt < 8; nt++) {
      float cs = 0.f;
#pragma unroll
      for (int mt = 0; mt < 4; mt++)
#pragma unroll
        for (int j = 0; j < 4; j++)
          cs = fmaf(aw[mt][j], fmaxf(acc1[mt][nt][j] + b1v[nt], 0.f), cs);
      cs += __shfl_xor(cs, 16); cs += __shfl_xor(cs, 32);
      if (quad == 0) atomicAdd(ph + bk * 512 + wave * 128 + nt * 16 + l15, cs);
    }
  }
}

// ---------------- softmax over K + one-pass moment sums -> stage ----------------
__global__ __launch_bounds__(256) void k_softmax_reduce(
    const float* __restrict__ dots, float* __restrict__ attn0,
    float* __restrict__ stage) {
  const int t = threadIdx.x;
  const int idx = blockIdx.x * 256 + t;
  const int b = idx >> 10, n = idx & 1023;
  const int lane = t & 63, wave = t >> 6;
  float vals[NK];
  float mx = -1e30f;
#pragma unroll
  for (int k = 0; k < NK; k++) {
    vals[k] = dots[(size_t)(b * NK + k) * NN + n];
    mx = fmaxf(mx, vals[k]);
  }
  float s = 0.f;
#pragma unroll
  for (int k = 0; k < NK; k++) { vals[k] = expf(vals[k] - mx); s += vals[k]; }
  const float inv = 1.0f / s;
  const float gx = -1.0f + GSTEP * (float)(n >> 5);
  const float gy = -1.0f + GSTEP * (float)(n & 31);
  const float gx2 = gx * gx, gy2 = gy * gy;
  float sk[NK][5];
#pragma unroll
  for (int k = 0; k < NK; k++) {
    const float a = vals[k] * inv;
    attn0[(size_t)(b * NK + k) * NN + n] = a;
    const float w = a + EPSA;
    sk[k][0] = a;
    sk[k][1] = a * gx;
    sk[k][2] = a * gy;
    sk[k][3] = w * gx2;
    sk[k][4] = w * gy2;
  }
#pragma unroll
  for (int m = 32; m >= 1; m >>= 1)
#pragma unroll
    for (int k = 0; k < NK; k++)
#pragma unroll
      for (int c = 0; c < 5; c++)
        sk[k][c] += __shfl_xor(sk[k][c], m);
  __shared__ float red[4][40];
  if (lane == 0) {
#pragma unroll
    for (int k = 0; k < NK; k++)
#pragma unroll
      for (int c = 0; c < 5; c++)
        red[wave][k * 5 + c] = sk[k][c];
  }
  __syncthreads();
  if (t < 40) {
    const float tot = red[0][t] + red[1][t] + red[2][t] + red[3][t];
    const int k = t / 5, c = t % 5;
    atomicAdd(&stage[(b * NK + k) * 8 + c], tot);
  }
}

// ---------------- kU: U = ph @ W2 + b2 -> bf16 (batched MFMA, M=64) ----------------
__global__ __launch_bounds__(256) void k_upd(
    const float* __restrict__ ph, const short* __restrict__ w2T,
    const float* __restrict__ b2, short* __restrict__ Ub) {
  __shared__ __align__(16) short A[64 * 264];
  const int ncol0 = blockIdx.x * 128;
  const int t = threadIdx.x;
  const int wave = t >> 6, lane = t & 63, l15 = lane & 15, quad = lane >> 4;
  const int r = t >> 2, sub = t & 3;
  floatx4 acc[4][2];
#pragma unroll
  for (int mt = 0; mt < 4; mt++)
#pragma unroll
    for (int nt = 0; nt < 2; nt++) acc[mt][nt] = (floatx4){0.f, 0.f, 0.f, 0.f};
#pragma unroll
  for (int half = 0; half < 2; half++) {
    if (half > 0) __syncthreads();
#pragma unroll
    for (int ii = 0; ii < 16; ii++) {
      const int d = sub * 4 + ii * 16;
      const float4 v = *(const float4*)(ph + r * 512 + half * 256 + d);
      short4v pk = {f2bf(v.x), f2bf(v.y), f2bf(v.z), f2bf(v.w)};
      *(short4v*)&A[r * 264 + d] = pk;
    }
    __syncthreads();
    const short* wp = w2T + (size_t)(ncol0 + wave * 32 + l15) * 512 + half * 256 + quad * 8;
#pragma unroll
    for (int kk = 0; kk < 8; kk++) {
      short8 af[4];
#pragma unroll
      for (int mt = 0; mt < 4; mt++)
        af[mt] = *(const short8*)&A[(mt * 16 + l15) * 264 + kk * 32 + quad * 8];
      short8 bf[2];
#pragma unroll
      for (int nt = 0; nt < 2; nt++)
        bf[nt] = *(const short8*)(wp + nt * 16 * 512 + kk * 32);
#pragma unroll
      for (int mt = 0; mt < 4; mt++)
#pragma unroll
        for (int nt = 0; nt < 2; nt++)
          acc[mt][nt] = __builtin_amdgcn_mfma_f32_16x16x32_bf16(af[mt], bf[nt], acc[mt][nt], 0, 0, 0);
    }
  }
#pragma unroll
  for (int nt = 0; nt < 2; nt++) {
    const int col = ncol0 + wave * 32 + nt * 16 + l15;
    const float bb = b2[col];
#pragma unroll
    for (int mt = 0; mt < 4; mt++)
#pragma unroll
      for (int j = 0; j < 4; j++)
        Ub[(mt * 16 + quad * 4 + j) * 256 + col] = f2bf(acc[mt][nt][j] + bb);
  }
}

// ---------------- kGates: GXH = [U|H] @ [wih^T|whh^T] -> bf16 ----------------
__global__ __launch_bounds__(256) void k_gates(
    const short* __restrict__ Ub, const float* __restrict__ sf,
    const short* __restrict__ wihB, const short* __restrict__ whhB,
    short* __restrict__ gxh) {
  __shared__ __align__(16) short A[64 * 264];
  const int c = blockIdx.x;          // 0..11
  const int isGX = (c < 6) ? 1 : 0;
  const int jb = (isGX ? c : c - 6) * 128;
  const int t = threadIdx.x;
  const int wave = t >> 6, lane = t & 63, l15 = lane & 15, quad = lane >> 4;
  const int r = t >> 2, sub = t & 3;
  if (isGX) {
#pragma unroll
    for (int ii = 0; ii < 8; ii++) {
      const int d = sub * 8 + ii * 32;
      *(short8*)&A[r * 264 + d] = *(const short8*)(Ub + r * 256 + d);
    }
  } else {
#pragma unroll
    for (int ii = 0; ii < 16; ii++) {
      const int d = sub * 4 + ii * 16;
      const float4 v = *(const float4*)(sf + r * 260 + d);
      short4v pk = {f2bf(v.x), f2bf(v.y), f2bf(v.z), f2bf(v.w)};
      *(short4v*)&A[r * 264 + d] = pk;
    }
  }
  __syncthreads();
  const short* B = isGX ? wihB : whhB;
  const short* wp = B + (size_t)(jb + wave * 32 + l15) * 256 + quad * 8;
  floatx4 acc[4][2];
#pragma unroll
  for (int mt = 0; mt < 4; mt++)
#pragma unroll
    for (int nt = 0; nt < 2; nt++) acc[mt][nt] = (floatx4){0.f, 0.f, 0.f, 0.f};
#pragma unroll
  for (int kk = 0; kk < 8; kk++) {
    short8 af[4];
#pragma unroll
    for (int mt = 0; mt < 4; mt++)
      af[mt] = *(const short8*)&A[(mt * 16 + l15) * 264 + kk * 32 + quad * 8];
    short8 bf[2];
#pragma unroll
    for (int nt = 0; nt < 2; nt++)
      bf[nt] = *(const short8*)(wp + nt * 16 * 256 + kk * 32);
#pragma unroll
    for (int mt = 0; mt < 4; mt++)
#pragma unroll
      for (int nt = 0; nt < 2; nt++)
        acc[mt][nt] = __builtin_amdgcn_mfma_f32_16x16x32_bf16(af[mt], bf[nt], acc[mt][nt], 0, 0, 0);
  }
  const int cb = (isGX ? 0 : 768) + jb;
#pragma unroll
  for (int mt = 0; mt < 4; mt++)
#pragma unroll
    for (int nt = 0; nt < 2; nt++)
#pragma unroll
      for (int j = 0; j < 4; j++)
        gxh[(mt * 16 + quad * 4 + j) * 1536 + cb + wave * 32 + nt * 16 + l15] = f2bf(acc[mt][nt][j]);
}

// ---------------- kSlot: GRU elementwise + LN + pos/scl + zero stage/ph ----------------
__global__ __launch_bounds__(256) void k_slot(
    const short* __restrict__ gxh, float* __restrict__ sf,
    const float* __restrict__ bih, const float* __restrict__ bhh,
    const float* __restrict__ nsg, const float* __restrict__ nsb,
    short* __restrict__ lnb16,
    float* __restrict__ pos, float* __restrict__ scl,
    float* __restrict__ stage, float* __restrict__ ph, const int mode) {
  const int bk = blockIdx.x, t = threadIdx.x;
  __shared__ float red[8];
  const float h = sf[bk * 260 + t];
  float ns;
  if (mode) {
    const float x0 = bf2f(gxh[bk * 1536 + t]);
    const float x1 = bf2f(gxh[bk * 1536 + 256 + t]);
    const float x2 = bf2f(gxh[bk * 1536 + 512 + t]);
    const float h0 = bf2f(gxh[bk * 1536 + 768 + t]);
    const float h1v = bf2f(gxh[bk * 1536 + 1024 + t]);
    const float h2 = bf2f(gxh[bk * 1536 + 1280 + t]);
    const float r = 1.0f / (1.0f + expf(-(x0 + bih[t] + h0 + bhh[t])));
    const float z = 1.0f / (1.0f + expf(-(x1 + bih[256 + t] + h1v + bhh[256 + t])));
    const float nw = tanhf(x2 + bih[512 + t] + r * (h2 + bhh[512 + t]));
    ns = (1.0f - z) * nw + z * h;
    sf[bk * 260 + t] = ns;
  } else {
    ns = h;
  }
  float s2 = ns, ss = ns * ns;
#pragma unroll
  for (int m = 32; m >= 1; m >>= 1) { s2 += __shfl_xor(s2, m); ss += __shfl_xor(ss, m); }
  const int wv = t >> 6;
  if ((t & 63) == 0) { red[wv] = s2; red[4 + wv] = ss; }
  __syncthreads();
  const float S = red[0] + red[1] + red[2] + red[3];
  const float SS = red[4] + red[5] + red[6] + red[7];
  const float mean = S * (1.0f / ND);
  const float var = SS * (1.0f / ND) - mean * mean;
  const float rstd = rsqrtf(var + LNEPS);
  lnb16[bk * 256 + t] = f2bf((ns - mean) * rstd * nsg[t] + nsb[t]);
  if (mode) {
    if (t == 0) {
      const float Sa = stage[bk * 8 + 0];
      const float G0 = stage[bk * 8 + 1];
      const float G1 = stage[bk * 8 + 2];
      const float Q0 = stage[bk * 8 + 3];
      const float Q1 = stage[bk * 8 + 4];
      const float W = Sa + (float)NN * EPSA;
      const float sc0 = sqrtf(fmaxf(Q0 - 2.0f * G0 * G0 + G0 * G0 * W, 0.f));
      const float sc1 = sqrtf(fmaxf(Q1 - 2.0f * G1 * G1 + G1 * G1 * W, 0.f));
      const float sc0c = fminf(fmaxf(sc0, 1e-3f), 2.0f);
      const float sc1c = fminf(fmaxf(sc1, 1e-3f), 2.0f);
      sf[bk * 260 + 256] = G0;
      sf[bk * 260 + 257] = G1;
      sf[bk * 260 + 258] = sc0c;
      sf[bk * 260 + 259] = sc1c;
      pos[bk * 2 + 0] = fminf(fmaxf(G0, -1.0f), 1.0f);
      pos[bk * 2 + 1] = fminf(fmaxf(G1, -1.0f), 1.0f);
      scl[bk * 2 + 0] = sc0c;
      scl[bk * 2 + 1] = sc1c;
    }
  } else {
    if (t < 2) {
      const float p = sf[bk * 260 + 256 + t];
      pos[bk * 2 + t] = fminf(fmaxf(p, -1.0f), 1.0f);
      const float sc = sf[bk * 260 + 258 + t];
      scl[bk * 2 + t] = fminf(fmaxf(sc, 1e-3f), 2.0f);
    }
  }
  __syncthreads();  // t==0's stage reads done before zeroing
  if (t < 8) stage[bk * 8 + t] = 0.f;
  ph[bk * 512 + t] = 0.f;
  ph[bk * 512 + 256 + t] = 0.f;
}

// ---------------- kQ: Q = lnv @ wq (bf16 out) + qb2 -> stage[.5] ----------------
__global__ __launch_bounds__(256) void k_q(
    const short* __restrict__ lnb16, const short* __restrict__ wqT,
    const float* __restrict__ b2, short* __restrict__ Qb,
    float* __restrict__ stage) {
  __shared__ __align__(16) short A[64 * 264];
  __shared__ float qred[256];
  const int ncol0 = blockIdx.x * 128;
  const int t = threadIdx.x;
  const int wave = t >> 6, lane = t & 63, l15 = lane & 15, quad = lane >> 4;
  const int r = t >> 2, sub = t & 3;
#pragma unroll
  for (int ii = 0; ii < 8; ii++) {
    const int d = sub * 8 + ii * 32;
    *(short8*)&A[r * 264 + d] = *(const short8*)(lnb16 + r * 256 + d);
  }
  __syncthreads();
  const short* wp = wqT + (size_t)(ncol0 + wave * 32 + l15) * 256 + quad * 8;
  floatx4 acc[4][2];
#pragma unroll
  for (int mt = 0; mt < 4; mt++)
#pragma unroll
    for (int nt = 0; nt < 2; nt++) acc[mt][nt] = (floatx4){0.f, 0.f, 0.f, 0.f};
#pragma unroll
  for (int kk = 0; kk < 8; kk++) {
    short8 af[4];
#pragma unroll
    for (int mt = 0; mt < 4; mt++)
      af[mt] = *(const short8*)&A[(mt * 16 + l15) * 264 + kk * 32 + quad * 8];
    short8 bf[2];
#pragma unroll
    for (int nt = 0; nt < 2; nt++)
      bf[nt] = *(const short8*)(wp + nt * 16 * 256 + kk * 32);
#pragma unroll
    for (int mt = 0; mt < 4; mt++)
#pragma unroll
      for (int nt = 0; nt < 2; nt++)
        acc[mt][nt] = __builtin_amdgcn_mfma_f32_16x16x32_bf16(af[mt], bf[nt], acc[mt][nt], 0, 0, 0);
  }
  float b2v[2];
#pragma unroll
  for (int nt = 0; nt < 2; nt++) b2v[nt] = b2[ncol0 + wave * 32 + nt * 16 + l15];
#pragma unroll
  for (int mt = 0; mt < 4; mt++)
#pragma unroll
    for (int j = 0; j < 4; j++) {
      float p = 0.f;
#pragma unroll
      for (int nt = 0; nt < 2; nt++) {
        const int col = ncol0 + wave * 32 + nt * 16 + l15;
        Qb[(mt * 16 + quad * 4 + j) * 256 + col] = f2bf(acc[mt][nt][j]);
        p = fmaf(acc[mt][nt][j], b2v[nt], p);
      }
      p += __shfl_xor(p, 1); p += __shfl_xor(p, 2);
      p += __shfl_xor(p, 4); p += __shfl_xor(p, 8);
      if (l15 == 0) qred[wave * 64 + mt * 16 + quad * 4 + j] = p;
    }
  __syncthreads();
  if (t < 64)
    atomicAdd(&stage[t * 8 + 5], qred[t] + qred[64 + t] + qred[128 + t] + qred[192 + t]);
}

// ---------------- kW2Q: w2q = Q @ ge_w2^T (fp32 out) ----------------
__global__ __launch_bounds__(256) void k_w2q(
    const short* __restrict__ Qb, const short* __restrict__ w2B,
    float* __restrict__ w2q) {
  __shared__ __align__(16) short A[64 * 264];
  const int jb = blockIdx.x * 128;
  const int t = threadIdx.x;
  const int wave = t >> 6, lane = t & 63, l15 = lane & 15, quad = lane >> 4;
  const int r = t >> 2, sub = t & 3;
#pragma unroll
  for (int ii = 0; ii < 8; ii++) {
    const int d = sub * 8 + ii * 32;
    *(short8*)&A[r * 264 + d] = *(const short8*)(Qb + r * 256 + d);
  }
  __syncthreads();
  const short* wp = w2B + (size_t)(jb + wave * 32 + l15) * 256 + quad * 8;
  floatx4 acc[4][2];
#pragma unroll
  for (int mt = 0; mt < 4; mt++)
#pragma unroll
    for (int nt = 0; nt < 2; nt++) acc[mt][nt] = (floatx4){0.f, 0.f, 0.f, 0.f};
#pragma unroll
  for (int kk = 0; kk < 8; kk++) {
    short8 af[4];
#pragma unroll
    for (int mt = 0; mt < 4; mt++)
      af[mt] = *(const short8*)&A[(mt * 16 + l15) * 264 + kk * 32 + quad * 8];
    short8 bf[2];
#pragma unroll
    for (int nt = 0; nt < 2; nt++)
      bf[nt] = *(const short8*)(wp + nt * 16 * 256 + kk * 32);
#pragma unroll
    for (int mt = 0; mt < 4; mt++)
#pragma unroll
      for (int nt = 0; nt < 2; nt++)
        acc[mt][nt] = __builtin_amdgcn_mfma_f32_16x16x32_bf16(af[mt], bf[nt], acc[mt][nt], 0, 0, 0);
  }
#pragma unroll
  for (int mt = 0; mt < 4; mt++)
#pragma unroll
    for (int nt = 0; nt < 2; nt++)
#pragma unroll
      for (int j = 0; j < 4; j++)
        w2q[(mt * 16 + quad * 4 + j) * 512 + jb + wave * 32 + nt * 16 + l15] = acc[mt][nt][j];
}

// ---------------- finalize ----------------
__global__ __launch_bounds__(256) void k_finalize(
    const float* __restrict__ sf, const float* __restrict__ attn0,
    const float* __restrict__ pos, const float* __restrict__ scl,
    const float* __restrict__ stage, float* __restrict__ out) {
  const int bk = blockIdx.x, t = threadIdx.x;
  out[bk * 260 + t] = sf[bk * 260 + t];
  if (t == 0) {
    const float Sa = stage[bk * 8 + 0];
    const float G0 = stage[bk * 8 + 1];
    const float G1 = stage[bk * 8 + 2];
    const float Q0 = stage[bk * 8 + 3];
    const float Q1 = stage[bk * 8 + 4];
    const float W = Sa + (float)NN * EPSA;
    const float sc0 = sqrtf(fmaxf(Q0 - 2.0f * G0 * G0 + G0 * G0 * W, 0.f));
    const float sc1 = sqrtf(fmaxf(Q1 - 2.0f * G1 * G1 + G1 * G1 * W, 0.f));
    out[bk * 260 + 256] = G0;
    out[bk * 260 + 257] = G1;
    out[bk * 260 + 258] = fminf(fmaxf(sc0, 1e-3f), 2.0f);
    out[bk * 260 + 259] = fminf(fmaxf(sc1, 1e-3f), 2.0f);
  }
  const float p0 = pos[bk * 2 + 0], p1 = pos[bk * 2 + 1];
  const float s0 = scl[bk * 2 + 0] * 5.0f, s1 = scl[bk * 2 + 1] * 5.0f;
#pragma unroll
  for (int i = 0; i < 4; i++) {
    const int n = t + 256 * i;
    out[16640 + bk * NN + n] = attn0[(size_t)bk * NN + n];
    const float gx = -1.0f + GSTEP * (float)(n >> 5);
    const float gy = -1.0f + GSTEP * (float)(n & 31);
    float2 v;
    v.x = (gx - p0) / s0;
    v.y = (gy - p1) / s1;
    *(float2*)(out + 16640 + 65536 + ((size_t)bk * NN + n) * 2) = v;
  }
}

extern "C" void kernel_launch(void* const* d_in, const int* in_sizes, int n_in,
                              void* d_out, int out_size, void* d_ws, size_t ws_size,
                              hipStream_t stream) {
  const float* inputs   = (const float*)d_in[0];
  const float* cond     = (const float*)d_in[1];
  const float* ni_g     = (const float*)d_in[2];
  const float* ni_b     = (const float*)d_in[3];
  const float* ns_g     = (const float*)d_in[4];
  const float* ns_b     = (const float*)d_in[5];
  const float* wq       = (const float*)d_in[6];
  const float* wk       = (const float*)d_in[7];
  const float* wv       = (const float*)d_in[8];
  const float* gp_w     = (const float*)d_in[9];
  const float* gp_b     = (const float*)d_in[10];
  const float* ge_ln_g  = (const float*)d_in[11];
  const float* ge_ln_b  = (const float*)d_in[12];
  const float* ge_w1    = (const float*)d_in[13];
  const float* ge_b1    = (const float*)d_in[14];
  const float* ge_w2    = (const float*)d_in[15];
  const float* ge_b2    = (const float*)d_in[16];
  const float* gru_wih  = (const float*)d_in[17];
  const float* gru_whh  = (const float*)d_in[18];
  const float* gru_bih  = (const float*)d_in[19];
  const float* gru_bhh  = (const float*)d_in[20];

  float* ws   = (float*)d_ws;
  float* kbuf = ws;                  // 8*1024*256
  float* vbuf = kbuf + 2097152;      // 8*1024*256
  float* sf   = vbuf + 2097152;      // 64*260
  float* w2qb = sf + 16640;          // 64*512
  float* posb = w2qb + 32768;        // 64*2 (padded)
  float* sclb = posb + 128;          // 64*2 (padded)
  float* dotsb = sclb + 128;         // 64*1024
  float* at0  = dotsb + 65536;       // 64*1024
  float* phb  = at0 + 65536;         // 64*512
  float* stag = phb + 32768;         // 64*8
  short* gxh  = (short*)(stag + 512);     // 64*1536 bf16
  short* Ub   = gxh + 98304;              // 64*256 bf16
  short* Qb   = Ub + 16384;               // 64*256 bf16
  short* lnb16 = Qb + 16384;              // 64*256 bf16
  short* w1T  = lnb16 + 16384;            // 512*256 bf16
  short* w2T  = w1T + 131072;             // 256*512 bf16
  short* wkT  = w2T + 131072;             // 256*256 bf16
  short* wvT  = wkT + 65536;              // 256*256 bf16
  short* wihB = wvT + 65536;              // 768*256 bf16
  short* whhB = wihB + 196608;            // 768*256 bf16
  short* wqT  = whhB + 196608;            // 256*256 bf16
  short* w2B  = wqT + 65536;              // 512*256 bf16

  float* out = (float*)d_out;

  hipMemcpyAsync(sf, cond, 16640 * sizeof(float), hipMemcpyDeviceToDevice, stream);

  k_cvt_all<<<3840, 256, 0, stream>>>(ge_w1, ge_w2, wk, wv, gru_wih, gru_whh, wq,
                                      w1T, w2T, wkT, wvT, wihB, whhB, wqT, w2B);
  k_gemm_kv_mfma<<<dim3(128, 1, 2), 256, 0, stream>>>(inputs, ni_g, ni_b,
                                                      wkT, wvT, kbuf, vbuf);
  k_slot<<<NBK, 256, 0, stream>>>(gxh, sf, gru_bih, gru_bhh, ns_g, ns_b,
                                  lnb16, posb, sclb, stag, phb, 0);
  k_q<<<2, 256, 0, stream>>>(lnb16, wqT, ge_b2, Qb, stag);
  k_w2q<<<4, 256, 0, stream>>>(Qb, w2B, w2qb);

  for (int s = 0; s < 4; s++) {
    k_fused_mfma<<<dim3(16, NBK), 256, 0, stream>>>(
        kbuf, posb, sclb, gp_w, gp_b, ge_ln_g, ge_ln_b, w1T, ge_b1,
        w2qb, dotsb, at0, stag, phb, 0);
    k_softmax_reduce<<<32, 256, 0, stream>>>(dotsb, at0, stag);
    if (s < 3) {
      k_fused_mfma<<<dim3(16, NBK), 256, 0, stream>>>(
          vbuf, posb, sclb, gp_w, gp_b, ge_ln_g, ge_ln_b, w1T, ge_b1,
          w2qb, dotsb, at0, stag, phb, 1);
      k_upd<<<2, 256, 0, stream>>>(phb, w2T, ge_b2, Ub);
      k_gates<<<12, 256, 0, stream>>>(Ub, sf, wihB, whhB, gxh);
      k_slot<<<NBK, 256, 0, stream>>>(gxh, sf, gru_bih, gru_bhh, ns_g, ns_b,
                                      lnb16, posb, sclb, stag, phb, 1);
      k_q<<<2, 256, 0, stream>>>(lnb16, wqT, ge_b2, Qb, stag);
      k_w2q<<<4, 256, 0, stream>>>(Qb, w2B, w2qb);
    }
  }

  k_finalize<<<NBK, 256, 0, stream>>>(sf, at0, posb, sclb, stag, out);
}

// Round 9
// 571.104 us; speedup vs baseline: 1.8323x; 1.8323x over previous
//
#include <hip/hip_runtime.h>
#include <math.h>

#define NB 8
#define NN 1024
#define NK 8
#define ND 256
#define ND2 512
#define NBK 64
#define EPSA 1e-8f
#define LNEPS 1e-5f
#define GSTEP (2.0f/31.0f)

using short8 = __attribute__((ext_vector_type(8))) short;
using short4v = __attribute__((ext_vector_type(4))) short;
using floatx4 = __attribute__((ext_vector_type(4))) float;

__device__ __forceinline__ short f2bf(float f) {
  unsigned u = __builtin_bit_cast(unsigned, f);
  u += 0x7fffu + ((u >> 16) & 1u);
  return (short)(u >> 16);
}
__device__ __forceinline__ float bf2f(short s) {
  unsigned u = ((unsigned)(unsigned short)s) << 16;
  return __builtin_bit_cast(float, u);
}

// ---------------- all weight conversions in one launch ----------------
__global__ __launch_bounds__(256) void k_cvt_all(
    const float* __restrict__ w1, const float* __restrict__ w2,
    const float* __restrict__ wk, const float* __restrict__ wv,
    const float* __restrict__ wih, const float* __restrict__ whh,
    const float* __restrict__ wq,
    short* __restrict__ w1T, short* __restrict__ w2T,
    short* __restrict__ wkT, short* __restrict__ wvT,
    short* __restrict__ wihB, short* __restrict__ whhB,
    short* __restrict__ wqT, short* __restrict__ w2B) {
  const int idx = blockIdx.x * 256 + threadIdx.x;
  if (idx < 131072) {
    const int n = idx >> 8, k = idx & 255;
    w1T[idx] = f2bf(w1[(size_t)k * 512 + n]);
  } else if (idx < 262144) {
    const int i = idx - 131072;
    const int n = i >> 9, k = i & 511;
    w2T[i] = f2bf(w2[(size_t)k * 256 + n]);
  } else if (idx < 327680) {
    const int i = idx - 262144;
    const int n = i >> 8, k = i & 255;
    wkT[i] = f2bf(wk[(size_t)k * 256 + n]);
  } else if (idx < 393216) {
    const int i = idx - 327680;
    const int n = i >> 8, k = i & 255;
    wvT[i] = f2bf(wv[(size_t)k * 256 + n]);
  } else if (idx < 589824) {
    const int i = idx - 393216;
    wihB[i] = f2bf(wih[i]);
  } else if (idx < 786432) {
    const int i = idx - 589824;
    whhB[i] = f2bf(whh[i]);
  } else if (idx < 851968) {
    const int i = idx - 786432;
    const int n = i >> 8, k = i & 255;
    wqT[i] = f2bf(wq[(size_t)k * 256 + n]);
  } else {
    const int i = idx - 851968;
    w2B[i] = f2bf(w2[i]);
  }
}

// ---------------- k/v projection via bf16 MFMA (LN stats inline) ----------------
__global__ __launch_bounds__(256, 2) void k_gemm_kv_mfma(
    const float* __restrict__ inp,
    const float* __restrict__ nig, const float* __restrict__ nib,
    const short* __restrict__ wkT, const short* __restrict__ wvT,
    float* __restrict__ kout, float* __restrict__ vout) {
  __shared__ __align__(16) short tln[64 * 264];
  const short* __restrict__ WT = blockIdx.z ? wvT : wkT;
  float* __restrict__ out = blockIdx.z ? vout : kout;
  const int row0 = blockIdx.x * 64;
  const int t = threadIdx.x;
  const int wave = t >> 6, lane = t & 63, l15 = lane & 15, quad = lane >> 4;
  {
    const int r = t >> 2, sub = t & 3;
    const float* xr = inp + (size_t)(row0 + r) * ND;
    float tv[64];
    float sum = 0.f, ssq = 0.f;
#pragma unroll
    for (int ii = 0; ii < 16; ii++) {
      const int d = sub * 4 + ii * 16;
      const float4 xv = *(const float4*)(xr + d);
      tv[ii * 4 + 0] = xv.x; sum += xv.x; ssq += xv.x * xv.x;
      tv[ii * 4 + 1] = xv.y; sum += xv.y; ssq += xv.y * xv.y;
      tv[ii * 4 + 2] = xv.z; sum += xv.z; ssq += xv.z * xv.z;
      tv[ii * 4 + 3] = xv.w; sum += xv.w; ssq += xv.w * xv.w;
    }
    sum += __shfl_xor(sum, 1); ssq += __shfl_xor(ssq, 1);
    sum += __shfl_xor(sum, 2); ssq += __shfl_xor(ssq, 2);
    const float mean = sum * (1.0f / ND);
    const float var = ssq * (1.0f / ND) - mean * mean;
    const float rstd = rsqrtf(var + LNEPS);
#pragma unroll
    for (int ii = 0; ii < 16; ii++) {
      const int d = sub * 4 + ii * 16;
      const float4 gg = *(const float4*)(nig + d);
      const float4 bb = *(const float4*)(nib + d);
      short4v pk;
      pk.x = f2bf((tv[ii * 4 + 0] - mean) * rstd * gg.x + bb.x);
      pk.y = f2bf((tv[ii * 4 + 1] - mean) * rstd * gg.y + bb.y);
      pk.z = f2bf((tv[ii * 4 + 2] - mean) * rstd * gg.z + bb.z);
      pk.w = f2bf((tv[ii * 4 + 3] - mean) * rstd * gg.w + bb.w);
      *(short4v*)&tln[r * 264 + d] = pk;
    }
  }
  __syncthreads();
  floatx4 acc[4][4];
#pragma unroll
  for (int mt = 0; mt < 4; mt++)
#pragma unroll
    for (int nt = 0; nt < 4; nt++) acc[mt][nt] = (floatx4){0.f, 0.f, 0.f, 0.f};
  const short* wp = WT + ((size_t)(wave * 64 + l15)) * 256 + quad * 8;
#pragma unroll
  for (int kk = 0; kk < 8; kk++) {
    short8 af[4];
#pragma unroll
    for (int mt = 0; mt < 4; mt++)
      af[mt] = *(const short8*)&tln[(mt * 16 + l15) * 264 + kk * 32 + quad * 8];
    short8 bf[4];
#pragma unroll
    for (int nt = 0; nt < 4; nt++)
      bf[nt] = *(const short8*)(wp + nt * 16 * 256 + kk * 32);
#pragma unroll
    for (int mt = 0; mt < 4; mt++)
#pragma unroll
      for (int nt = 0; nt < 4; nt++)
        acc[mt][nt] = __builtin_amdgcn_mfma_f32_16x16x32_bf16(af[mt], bf[nt], acc[mt][nt], 0, 0, 0);
  }
#pragma unroll
  for (int mt = 0; mt < 4; mt++)
#pragma unroll
    for (int nt = 0; nt < 4; nt++)
#pragma unroll
      for (int j = 0; j < 4; j++)
        out[(size_t)(row0 + mt * 16 + quad * 4 + j) * ND + wave * 64 + nt * 16 + l15] = acc[mt][nt][j];
}

// ---------------- fused grid_enc pass: GEMM1 only (W2 folded out) ----------------
#define LDA 264

__global__ __launch_bounds__(256, 2) void k_fused_mfma(
    const float* __restrict__ kv,
    const float* __restrict__ pos, const float* __restrict__ scl,
    const float* __restrict__ gpw, const float* __restrict__ gpb,
    const float* __restrict__ lng, const float* __restrict__ lnb,
    const short* __restrict__ w1T, const float* __restrict__ b1,
    const float* __restrict__ w2q, float* __restrict__ dots,
    const float* __restrict__ attn0, const float* __restrict__ stage,
    float* __restrict__ ph, const int mode) {
  __shared__ __align__(16) short tln[64 * LDA];  // 33 KB; dred aliases after barrier

  const int bk = blockIdx.y;
  const int n0 = blockIdx.x * 64;
  const int b = bk >> 3;
  const int t = threadIdx.x;
  const int wave = t >> 6;
  const int lane = t & 63;
  const int l15 = lane & 15;
  const int quad = lane >> 4;

  // ---- Phase A: tln = LN(kv + rel_enc) -> bf16 LDS (64 rows, 4 thr/row) ----
  {
    const float p0 = pos[bk * 2 + 0], p1 = pos[bk * 2 + 1];
    const float s0i = 1.0f / (scl[bk * 2 + 0] * 5.0f);
    const float s1i = 1.0f / (scl[bk * 2 + 1] * 5.0f);
    const int r = t >> 2;
    const int sub = t & 3;
    const int n = n0 + r;
    const float gx = -1.0f + GSTEP * (float)(n >> 5);
    const float gy = -1.0f + GSTEP * (float)(n & 31);
    const float rg0 = (gx - p0) * s0i;
    const float rg1 = (gy - p1) * s1i;
    const float* kvrow = kv + (size_t)(b * NN + n) * ND;
    float tv[64];
    float sum = 0.f, ssq = 0.f;
#pragma unroll
    for (int ii = 0; ii < 16; ii++) {
      const int d = sub * 4 + ii * 16;
      const float4 kv4 = *(const float4*)(kvrow + d);
      const float4 wa = *(const float4*)(gpw + d);
      const float4 wb = *(const float4*)(gpw + ND + d);
      const float4 pb = *(const float4*)(gpb + d);
      float v0 = kv4.x + rg0 * wa.x + rg1 * wb.x + pb.x;
      float v1 = kv4.y + rg0 * wa.y + rg1 * wb.y + pb.y;
      float v2 = kv4.z + rg0 * wa.z + rg1 * wb.z + pb.z;
      float v3 = kv4.w + rg0 * wa.w + rg1 * wb.w + pb.w;
      tv[ii * 4 + 0] = v0; sum += v0; ssq += v0 * v0;
      tv[ii * 4 + 1] = v1; sum += v1; ssq += v1 * v1;
      tv[ii * 4 + 2] = v2; sum += v2; ssq += v2 * v2;
      tv[ii * 4 + 3] = v3; sum += v3; ssq += v3 * v3;
    }
    sum += __shfl_xor(sum, 1); ssq += __shfl_xor(ssq, 1);
    sum += __shfl_xor(sum, 2); ssq += __shfl_xor(ssq, 2);
    const float mean = sum * (1.0f / ND);
    const float var = ssq * (1.0f / ND) - mean * mean;
    const float rstd = rsqrtf(var + LNEPS);
#pragma unroll
    for (int ii = 0; ii < 16; ii++) {
      const int d = sub * 4 + ii * 16;
      const float4 gg = *(const float4*)(lng + d);
      const float4 bb = *(const float4*)(lnb + d);
      short4v pk;
      pk.x = f2bf((tv[ii * 4 + 0] - mean) * rstd * gg.x + bb.x);
      pk.y = f2bf((tv[ii * 4 + 1] - mean) * rstd * gg.y + bb.y);
      pk.z = f2bf((tv[ii * 4 + 2] - mean) * rstd * gg.z + bb.z);
      pk.w = f2bf((tv[ii * 4 + 3] - mean) * rstd * gg.w + bb.w);
      *(short4v*)&tln[r * LDA + d] = pk;
    }
  }
  __syncthreads();

  // ---- GEMM1: h1 = tln @ W1T^T (relu+bias in epilogue). Wave owns 128 cols. ----
  floatx4 acc1[4][8];
#pragma unroll
  for (int mt = 0; mt < 4; mt++)
#pragma unroll
    for (int nt = 0; nt < 8; nt++) acc1[mt][nt] = (floatx4){0.f, 0.f, 0.f, 0.f};

  const short* w1p = w1T + ((size_t)(wave * 128 + l15)) * 256 + quad * 8;
#pragma unroll
  for (int kk = 0; kk < 8; kk++) {
    short8 af[4];
#pragma unroll
    for (int mt = 0; mt < 4; mt++)
      af[mt] = *(const short8*)&tln[(mt * 16 + l15) * LDA + kk * 32 + quad * 8];
    short8 bf[8];
#pragma unroll
    for (int nt = 0; nt < 8; nt++)
      bf[nt] = *(const short8*)(w1p + nt * 16 * 256 + kk * 32);
#pragma unroll
    for (int mt = 0; mt < 4; mt++)
#pragma unroll
      for (int nt = 0; nt < 8; nt++)
        acc1[mt][nt] = __builtin_amdgcn_mfma_f32_16x16x32_bf16(af[mt], bf[nt], acc1[mt][nt], 0, 0, 0);
  }

  float b1v[8];
#pragma unroll
  for (int nt = 0; nt < 8; nt++) b1v[nt] = b1[wave * 128 + nt * 16 + l15];

  if (mode == 0) {
    float w2qv[8];
#pragma unroll
    for (int nt = 0; nt < 8; nt++) w2qv[nt] = w2q[bk * 512 + wave * 128 + nt * 16 + l15];
    const float qb2 = stage[bk * 8 + 5];
    __syncthreads();  // all tln reads done; alias as dred
    float* dred = (float*)tln;
#pragma unroll
    for (int mt = 0; mt < 4; mt++)
#pragma unroll
      for (int j = 0; j < 4; j++) {
        float p = 0.f;
#pragma unroll
        for (int nt = 0; nt < 8; nt++)
          p = fmaf(fmaxf(acc1[mt][nt][j] + b1v[nt], 0.f), w2qv[nt], p);
        p += __shfl_xor(p, 1); p += __shfl_xor(p, 2);
        p += __shfl_xor(p, 4); p += __shfl_xor(p, 8);
        if (l15 == 0) dred[wave * 64 + mt * 16 + quad * 4 + j] = p;
      }
    __syncthreads();
    if (t < 64) {
      const float s = dred[t] + dred[64 + t] + dred[128 + t] + dred[192 + t];
      dots[bk * NN + n0 + t] = (s + qb2) * 0.0625f;
    }
  } else {
    const float dn = 1.0f / (stage[bk * 8 + 0] + (float)NN * EPSA);
    float aw[4][4];
#pragma unroll
    for (int mt = 0; mt < 4; mt++)
#pragma unroll
      for (int j = 0; j < 4; j++)
        aw[mt][j] = (attn0[bk * NN + n0 + mt * 16 + quad * 4 + j] + EPSA) * dn;
#pragma unroll
    for (int nt = 0; nt < 8; nt++) {
      float cs = 0.f;
#pragma unroll
      for (int mt = 0; mt < 4; mt++)
#pragma unroll
        for (int j = 0; j < 4; j++)
          cs = fmaf(aw[mt][j], fmaxf(acc1[mt][nt][j] + b1v[nt], 0.f), cs);
      cs += __shfl_xor(cs, 16); cs += __shfl_xor(cs, 32);
      if (quad == 0) atomicAdd(ph + bk * 512 + wave * 128 + nt * 16 + l15, cs);
    }
  }
}

// ---------------- softmax over K + one-pass moment sums -> stage ----------------
__global__ __launch_bounds__(256) void k_softmax_reduce(
    const float* __restrict__ dots, float* __restrict__ attn0,
    float* __restrict__ stage) {
  const int t = threadIdx.x;
  const int idx = blockIdx.x * 256 + t;
  const int b = idx >> 10, n = idx & 1023;
  const int lane = t & 63, wave = t >> 6;
  float vals[NK];
  float mx = -1e30f;
#pragma unroll
  for (int k = 0; k < NK; k++) {
    vals[k] = dots[(size_t)(b * NK + k) * NN + n];
    mx = fmaxf(mx, vals[k]);
  }
  float s = 0.f;
#pragma unroll
  for (int k = 0; k < NK; k++) { vals[k] = expf(vals[k] - mx); s += vals[k]; }
  const float inv = 1.0f / s;
  const float gx = -1.0f + GSTEP * (float)(n >> 5);
  const float gy = -1.0f + GSTEP * (float)(n & 31);
  const float gx2 = gx * gx, gy2 = gy * gy;
  float sk[NK][5];
#pragma unroll
  for (int k = 0; k < NK; k++) {
    const float a = vals[k] * inv;
    attn0[(size_t)(b * NK + k) * NN + n] = a;
    const float w = a + EPSA;
    sk[k][0] = a;
    sk[k][1] = a * gx;
    sk[k][2] = a * gy;
    sk[k][3] = w * gx2;
    sk[k][4] = w * gy2;
  }
#pragma unroll
  for (int m = 32; m >= 1; m >>= 1)
#pragma unroll
    for (int k = 0; k < NK; k++)
#pragma unroll
      for (int c = 0; c < 5; c++)
        sk[k][c] += __shfl_xor(sk[k][c], m);
  __shared__ float red[4][40];
  if (lane == 0) {
#pragma unroll
    for (int k = 0; k < NK; k++)
#pragma unroll
      for (int c = 0; c < 5; c++)
        red[wave][k * 5 + c] = sk[k][c];
  }
  __syncthreads();
  if (t < 40) {
    const float tot = red[0][t] + red[1][t] + red[2][t] + red[3][t];
    const int k = t / 5, c = t % 5;
    atomicAdd(&stage[(b * NK + k) * 8 + c], tot);
  }
}

// ---------------- kU: U = ph @ W2 + b2 -> bf16 (batched MFMA, M=64) ----------------
__global__ __launch_bounds__(256) void k_upd(
    const float* __restrict__ ph, const short* __restrict__ w2T,
    const float* __restrict__ b2, short* __restrict__ Ub) {
  __shared__ __align__(16) short A[64 * 264];
  const int ncol0 = blockIdx.x * 128;
  const int t = threadIdx.x;
  const int wave = t >> 6, lane = t & 63, l15 = lane & 15, quad = lane >> 4;
  const int r = t >> 2, sub = t & 3;
  floatx4 acc[4][2];
#pragma unroll
  for (int mt = 0; mt < 4; mt++)
#pragma unroll
    for (int nt = 0; nt < 2; nt++) acc[mt][nt] = (floatx4){0.f, 0.f, 0.f, 0.f};
#pragma unroll
  for (int half = 0; half < 2; half++) {
    if (half > 0) __syncthreads();
#pragma unroll
    for (int ii = 0; ii < 16; ii++) {
      const int d = sub * 4 + ii * 16;
      const float4 v = *(const float4*)(ph + r * 512 + half * 256 + d);
      short4v pk = {f2bf(v.x), f2bf(v.y), f2bf(v.z), f2bf(v.w)};
      *(short4v*)&A[r * 264 + d] = pk;
    }
    __syncthreads();
    const short* wp = w2T + (size_t)(ncol0 + wave * 32 + l15) * 512 + half * 256 + quad * 8;
#pragma unroll
    for (int kk = 0; kk < 8; kk++) {
      short8 af[4];
#pragma unroll
      for (int mt = 0; mt < 4; mt++)
        af[mt] = *(const short8*)&A[(mt * 16 + l15) * 264 + kk * 32 + quad * 8];
      short8 bf[2];
#pragma unroll
      for (int nt = 0; nt < 2; nt++)
        bf[nt] = *(const short8*)(wp + nt * 16 * 512 + kk * 32);
#pragma unroll
      for (int mt = 0; mt < 4; mt++)
#pragma unroll
        for (int nt = 0; nt < 2; nt++)
          acc[mt][nt] = __builtin_amdgcn_mfma_f32_16x16x32_bf16(af[mt], bf[nt], acc[mt][nt], 0, 0, 0);
    }
  }
#pragma unroll
  for (int nt = 0; nt < 2; nt++) {
    const int col = ncol0 + wave * 32 + nt * 16 + l15;
    const float bb = b2[col];
#pragma unroll
    for (int mt = 0; mt < 4; mt++)
#pragma unroll
      for (int j = 0; j < 4; j++)
        Ub[(mt * 16 + quad * 4 + j) * 256 + col] = f2bf(acc[mt][nt][j] + bb);
  }
}

// ---------------- kGates: GXH = [U|H] @ [wih^T|whh^T] -> bf16 ----------------
__global__ __launch_bounds__(256) void k_gates(
    const short* __restrict__ Ub, const float* __restrict__ sf,
    const short* __restrict__ wihB, const short* __restrict__ whhB,
    short* __restrict__ gxh) {
  __shared__ __align__(16) short A[64 * 264];
  const int c = blockIdx.x;          // 0..11
  const int isGX = (c < 6) ? 1 : 0;
  const int jb = (isGX ? c : c - 6) * 128;
  const int t = threadIdx.x;
  const int wave = t >> 6, lane = t & 63, l15 = lane & 15, quad = lane >> 4;
  const int r = t >> 2, sub = t & 3;
  if (isGX) {
#pragma unroll
    for (int ii = 0; ii < 8; ii++) {
      const int d = sub * 8 + ii * 32;
      *(short8*)&A[r * 264 + d] = *(const short8*)(Ub + r * 256 + d);
    }
  } else {
#pragma unroll
    for (int ii = 0; ii < 16; ii++) {
      const int d = sub * 4 + ii * 16;
      const float4 v = *(const float4*)(sf + r * 260 + d);
      short4v pk = {f2bf(v.x), f2bf(v.y), f2bf(v.z), f2bf(v.w)};
      *(short4v*)&A[r * 264 + d] = pk;
    }
  }
  __syncthreads();
  const short* B = isGX ? wihB : whhB;
  const short* wp = B + (size_t)(jb + wave * 32 + l15) * 256 + quad * 8;
  floatx4 acc[4][2];
#pragma unroll
  for (int mt = 0; mt < 4; mt++)
#pragma unroll
    for (int nt = 0; nt < 2; nt++) acc[mt][nt] = (floatx4){0.f, 0.f, 0.f, 0.f};
#pragma unroll
  for (int kk = 0; kk < 8; kk++) {
    short8 af[4];
#pragma unroll
    for (int mt = 0; mt < 4; mt++)
      af[mt] = *(const short8*)&A[(mt * 16 + l15) * 264 + kk * 32 + quad * 8];
    short8 bf[2];
#pragma unroll
    for (int nt = 0; nt < 2; nt++)
      bf[nt] = *(const short8*)(wp + nt * 16 * 256 + kk * 32);
#pragma unroll
    for (int mt = 0; mt < 4; mt++)
#pragma unroll
      for (int nt = 0; nt < 2; nt++)
        acc[mt][nt] = __builtin_amdgcn_mfma_f32_16x16x32_bf16(af[mt], bf[nt], acc[mt][nt], 0, 0, 0);
  }
  const int cb = (isGX ? 0 : 768) + jb;
#pragma unroll
  for (int mt = 0; mt < 4; mt++)
#pragma unroll
    for (int nt = 0; nt < 2; nt++)
#pragma unroll
      for (int j = 0; j < 4; j++)
        gxh[(mt * 16 + quad * 4 + j) * 1536 + cb + wave * 32 + nt * 16 + l15] = f2bf(acc[mt][nt][j]);
}

// ---------------- kSlot: GRU elementwise + LN + pos/scl + zero stage/ph ----------------
__global__ __launch_bounds__(256) void k_slot(
    const short* __restrict__ gxh, float* __restrict__ sf,
    const float* __restrict__ bih, const float* __restrict__ bhh,
    const float* __restrict__ nsg, const float* __restrict__ nsb,
    short* __restrict__ lnb16,
    float* __restrict__ pos, float* __restrict__ scl,
    float* __restrict__ stage, float* __restrict__ ph, const int mode) {
  const int bk = blockIdx.x, t = threadIdx.x;
  __shared__ float red[8];
  const float h = sf[bk * 260 + t];
  float ns;
  if (mode) {
    const float x0 = bf2f(gxh[bk * 1536 + t]);
    const float x1 = bf2f(gxh[bk * 1536 + 256 + t]);
    const float x2 = bf2f(gxh[bk * 1536 + 512 + t]);
    const float h0 = bf2f(gxh[bk * 1536 + 768 + t]);
    const float h1v = bf2f(gxh[bk * 1536 + 1024 + t]);
    const float h2 = bf2f(gxh[bk * 1536 + 1280 + t]);
    const float r = 1.0f / (1.0f + expf(-(x0 + bih[t] + h0 + bhh[t])));
    const float z = 1.0f / (1.0f + expf(-(x1 + bih[256 + t] + h1v + bhh[256 + t])));
    const float nw = tanhf(x2 + bih[512 + t] + r * (h2 + bhh[512 + t]));
    ns = (1.0f - z) * nw + z * h;
    sf[bk * 260 + t] = ns;
  } else {
    ns = h;
  }
  float s2 = ns, ss = ns * ns;
#pragma unroll
  for (int m = 32; m >= 1; m >>= 1) { s2 += __shfl_xor(s2, m); ss += __shfl_xor(ss, m); }
  const int wv = t >> 6;
  if ((t & 63) == 0) { red[wv] = s2; red[4 + wv] = ss; }
  __syncthreads();
  const float S = red[0] + red[1] + red[2] + red[3];
  const float SS = red[4] + red[5] + red[6] + red[7];
  const float mean = S * (1.0f / ND);
  const float var = SS * (1.0f / ND) - mean * mean;
  const float rstd = rsqrtf(var + LNEPS);
  lnb16[bk * 256 + t] = f2bf((ns - mean) * rstd * nsg[t] + nsb[t]);
  if (mode) {
    if (t == 0) {
      const float Sa = stage[bk * 8 + 0];
      const float G0 = stage[bk * 8 + 1];
      const float G1 = stage[bk * 8 + 2];
      const float Q0 = stage[bk * 8 + 3];
      const float Q1 = stage[bk * 8 + 4];
      const float W = Sa + (float)NN * EPSA;
      const float sc0 = sqrtf(fmaxf(Q0 - 2.0f * G0 * G0 + G0 * G0 * W, 0.f));
      const float sc1 = sqrtf(fmaxf(Q1 - 2.0f * G1 * G1 + G1 * G1 * W, 0.f));
      const float sc0c = fminf(fmaxf(sc0, 1e-3f), 2.0f);
      const float sc1c = fminf(fmaxf(sc1, 1e-3f), 2.0f);
      sf[bk * 260 + 256] = G0;
      sf[bk * 260 + 257] = G1;
      sf[bk * 260 + 258] = sc0c;
      sf[bk * 260 + 259] = sc1c;
      pos[bk * 2 + 0] = fminf(fmaxf(G0, -1.0f), 1.0f);
      pos[bk * 2 + 1] = fminf(fmaxf(G1, -1.0f), 1.0f);
      scl[bk * 2 + 0] = sc0c;
      scl[bk * 2 + 1] = sc1c;
    }
  } else {
    if (t < 2) {
      const float p = sf[bk * 260 + 256 + t];
      pos[bk * 2 + t] = fminf(fmaxf(p, -1.0f), 1.0f);
      const float sc = sf[bk * 260 + 258 + t];
      scl[bk * 2 + t] = fminf(fmaxf(sc, 1e-3f), 2.0f);
    }
  }
  __syncthreads();  // t==0's stage reads done before zeroing
  if (t < 8) stage[bk * 8 + t] = 0.f;
  ph[bk * 512 + t] = 0.f;
  ph[bk * 512 + 256 + t] = 0.f;
}

// ---------------- kQ: Q = lnv @ wq (bf16 out) + qb2 -> stage[.5] ----------------
__global__ __launch_bounds__(256) void k_q(
    const short* __restrict__ lnb16, const short* __restrict__ wqT,
    const float* __restrict__ b2, short* __restrict__ Qb,
    float* __restrict__ stage) {
  __shared__ __align__(16) short A[64 * 264];
  __shared__ float qred[256];
  const int ncol0 = blockIdx.x * 128;
  const int t = threadIdx.x;
  const int wave = t >> 6, lane = t & 63, l15 = lane & 15, quad = lane >> 4;
  const int r = t >> 2, sub = t & 3;
#pragma unroll
  for (int ii = 0; ii < 8; ii++) {
    const int d = sub * 8 + ii * 32;
    *(short8*)&A[r * 264 + d] = *(const short8*)(lnb16 + r * 256 + d);
  }
  __syncthreads();
  const short* wp = wqT + (size_t)(ncol0 + wave * 32 + l15) * 256 + quad * 8;
  floatx4 acc[4][2];
#pragma unroll
  for (int mt = 0; mt < 4; mt++)
#pragma unroll
    for (int nt = 0; nt < 2; nt++) acc[mt][nt] = (floatx4){0.f, 0.f, 0.f, 0.f};
#pragma unroll
  for (int kk = 0; kk < 8; kk++) {
    short8 af[4];
#pragma unroll
    for (int mt = 0; mt < 4; mt++)
      af[mt] = *(const short8*)&A[(mt * 16 + l15) * 264 + kk * 32 + quad * 8];
    short8 bf[2];
#pragma unroll
    for (int nt = 0; nt < 2; nt++)
      bf[nt] = *(const short8*)(wp + nt * 16 * 256 + kk * 32);
#pragma unroll
    for (int mt = 0; mt < 4; mt++)
#pragma unroll
      for (int nt = 0; nt < 2; nt++)
        acc[mt][nt] = __builtin_amdgcn_mfma_f32_16x16x32_bf16(af[mt], bf[nt], acc[mt][nt], 0, 0, 0);
  }
  float b2v[2];
#pragma unroll
  for (int nt = 0; nt < 2; nt++) b2v[nt] = b2[ncol0 + wave * 32 + nt * 16 + l15];
#pragma unroll
  for (int mt = 0; mt < 4; mt++)
#pragma unroll
    for (int j = 0; j < 4; j++) {
      float p = 0.f;
#pragma unroll
      for (int nt = 0; nt < 2; nt++) {
        const int col = ncol0 + wave * 32 + nt * 16 + l15;
        Qb[(mt * 16 + quad * 4 + j) * 256 + col] = f2bf(acc[mt][nt][j]);
        p = fmaf(acc[mt][nt][j], b2v[nt], p);
      }
      p += __shfl_xor(p, 1); p += __shfl_xor(p, 2);
      p += __shfl_xor(p, 4); p += __shfl_xor(p, 8);
      if (l15 == 0) qred[wave * 64 + mt * 16 + quad * 4 + j] = p;
    }
  __syncthreads();
  if (t < 64)
    atomicAdd(&stage[t * 8 + 5], qred[t] + qred[64 + t] + qred[128 + t] + qred[192 + t]);
}

// ---------------- kW2Q: w2q = Q @ ge_w2^T (fp32 out) ----------------
__global__ __launch_bounds__(256) void k_w2q(
    const short* __restrict__ Qb, const short* __restrict__ w2B,
    float* __restrict__ w2q) {
  __shared__ __align__(16) short A[64 * 264];
  const int jb = blockIdx.x * 128;
  const int t = threadIdx.x;
  const int wave = t >> 6, lane = t & 63, l15 = lane & 15, quad = lane >> 4;
  const int r = t >> 2, sub = t & 3;
#pragma unroll
  for (int ii = 0; ii < 8; ii++) {
    const int d = sub * 8 + ii * 32;
    *(short8*)&A[r * 264 + d] = *(const short8*)(Qb + r * 256 + d);
  }
  __syncthreads();
  const short* wp = w2B + (size_t)(jb + wave * 32 + l15) * 256 + quad * 8;
  floatx4 acc[4][2];
#pragma unroll
  for (int mt = 0; mt < 4; mt++)
#pragma unroll
    for (int nt = 0; nt < 2; nt++) acc[mt][nt] = (floatx4){0.f, 0.f, 0.f, 0.f};
#pragma unroll
  for (int kk = 0; kk < 8; kk++) {
    short8 af[4];
#pragma unroll
    for (int mt = 0; mt < 4; mt++)
      af[mt] = *(const short8*)&A[(mt * 16 + l15) * 264 + kk * 32 + quad * 8];
    short8 bf[2];
#pragma unroll
    for (int nt = 0; nt < 2; nt++)
      bf[nt] = *(const short8*)(wp + nt * 16 * 256 + kk * 32);
#pragma unroll
    for (int mt = 0; mt < 4; mt++)
#pragma unroll
      for (int nt = 0; nt < 2; nt++)
        acc[mt][nt] = __builtin_amdgcn_mfma_f32_16x16x32_bf16(af[mt], bf[nt], acc[mt][nt], 0, 0, 0);
  }
#pragma unroll
  for (int mt = 0; mt < 4; mt++)
#pragma unroll
    for (int nt = 0; nt < 2; nt++)
#pragma unroll
      for (int j = 0; j < 4; j++)
        w2q[(mt * 16 + quad * 4 + j) * 512 + jb + wave * 32 + nt * 16 + l15] = acc[mt][nt][j];
}

// ---------------- finalize ----------------
__global__ __launch_bounds__(256) void k_finalize(
    const float* __restrict__ sf, const float* __restrict__ attn0,
    const float* __restrict__ pos, const float* __restrict__ scl,
    const float* __restrict__ stage, float* __restrict__ out) {
  const int bk = blockIdx.x, t = threadIdx.x;
  out[bk * 260 + t] = sf[bk * 260 + t];
  if (t == 0) {
    const float Sa = stage[bk * 8 + 0];
    const float G0 = stage[bk * 8 + 1];
    const float G1 = stage[bk * 8 + 2];
    const float Q0 = stage[bk * 8 + 3];
    const float Q1 = stage[bk * 8 + 4];
    const float W = Sa + (float)NN * EPSA;
    const float sc0 = sqrtf(fmaxf(Q0 - 2.0f * G0 * G0 + G0 * G0 * W, 0.f));
    const float sc1 = sqrtf(fmaxf(Q1 - 2.0f * G1 * G1 + G1 * G1 * W, 0.f));
    out[bk * 260 + 256] = G0;
    out[bk * 260 + 257] = G1;
    out[bk * 260 + 258] = fminf(fmaxf(sc0, 1e-3f), 2.0f);
    out[bk * 260 + 259] = fminf(fmaxf(sc1, 1e-3f), 2.0f);
  }
  const float p0 = pos[bk * 2 + 0], p1 = pos[bk * 2 + 1];
  const float s0 = scl[bk * 2 + 0] * 5.0f, s1 = scl[bk * 2 + 1] * 5.0f;
#pragma unroll
  for (int i = 0; i < 4; i++) {
    const int n = t + 256 * i;
    out[16640 + bk * NN + n] = attn0[(size_t)bk * NN + n];
    const float gx = -1.0f + GSTEP * (float)(n >> 5);
    const float gy = -1.0f + GSTEP * (float)(n & 31);
    float2 v;
    v.x = (gx - p0) / s0;
    v.y = (gy - p1) / s1;
    *(float2*)(out + 16640 + 65536 + ((size_t)bk * NN + n) * 2) = v;
  }
}

extern "C" void kernel_launch(void* const* d_in, const int* in_sizes, int n_in,
                              void* d_out, int out_size, void* d_ws, size_t ws_size,
                              hipStream_t stream) {
  const float* inputs   = (const float*)d_in[0];
  const float* cond     = (const float*)d_in[1];
  const float* ni_g     = (const float*)d_in[2];
  const float* ni_b     = (const float*)d_in[3];
  const float* ns_g     = (const float*)d_in[4];
  const float* ns_b     = (const float*)d_in[5];
  const float* wq       = (const float*)d_in[6];
  const float* wk       = (const float*)d_in[7];
  const float* wv       = (const float*)d_in[8];
  const float* gp_w     = (const float*)d_in[9];
  const float* gp_b     = (const float*)d_in[10];
  const float* ge_ln_g  = (const float*)d_in[11];
  const float* ge_ln_b  = (const float*)d_in[12];
  const float* ge_w1    = (const float*)d_in[13];
  const float* ge_b1    = (const float*)d_in[14];
  const float* ge_w2    = (const float*)d_in[15];
  const float* ge_b2    = (const float*)d_in[16];
  const float* gru_wih  = (const float*)d_in[17];
  const float* gru_whh  = (const float*)d_in[18];
  const float* gru_bih  = (const float*)d_in[19];
  const float* gru_bhh  = (const float*)d_in[20];

  float* ws   = (float*)d_ws;
  float* kbuf = ws;                  // 8*1024*256
  float* vbuf = kbuf + 2097152;      // 8*1024*256
  float* sf   = vbuf + 2097152;      // 64*260
  float* w2qb = sf + 16640;          // 64*512
  float* posb = w2qb + 32768;        // 64*2 (padded)
  float* sclb = posb + 128;          // 64*2 (padded)
  float* dotsb = sclb + 128;         // 64*1024
  float* at0  = dotsb + 65536;       // 64*1024
  float* phb  = at0 + 65536;         // 64*512
  float* stag = phb + 32768;         // 64*8
  short* gxh  = (short*)(stag + 512);     // 64*1536 bf16
  short* Ub   = gxh + 98304;              // 64*256 bf16
  short* Qb   = Ub + 16384;               // 64*256 bf16
  short* lnb16 = Qb + 16384;              // 64*256 bf16
  short* w1T  = lnb16 + 16384;            // 512*256 bf16
  short* w2T  = w1T + 131072;             // 256*512 bf16
  short* wkT  = w2T + 131072;             // 256*256 bf16
  short* wvT  = wkT + 65536;              // 256*256 bf16
  short* wihB = wvT + 65536;              // 768*256 bf16
  short* whhB = wihB + 196608;            // 768*256 bf16
  short* wqT  = whhB + 196608;            // 256*256 bf16
  short* w2B  = wqT + 65536;              // 512*256 bf16

  float* out = (float*)d_out;

  hipMemcpyAsync(sf, cond, 16640 * sizeof(float), hipMemcpyDeviceToDevice, stream);

  k_cvt_all<<<3840, 256, 0, stream>>>(ge_w1, ge_w2, wk, wv, gru_wih, gru_whh, wq,
                                      w1T, w2T, wkT, wvT, wihB, whhB, wqT, w2B);
  k_gemm_kv_mfma<<<dim3(128, 1, 2), 256, 0, stream>>>(inputs, ni_g, ni_b,
                                                      wkT, wvT, kbuf, vbuf);
  k_slot<<<NBK, 256, 0, stream>>>(gxh, sf, gru_bih, gru_bhh, ns_g, ns_b,
                                  lnb16, posb, sclb, stag, phb, 0);
  k_q<<<2, 256, 0, stream>>>(lnb16, wqT, ge_b2, Qb, stag);
  k_w2q<<<4, 256, 0, stream>>>(Qb, w2B, w2qb);

  for (int s = 0; s < 4; s++) {
    k_fused_mfma<<<dim3(16, NBK), 256, 0, stream>>>(
        kbuf, posb, sclb, gp_w, gp_b, ge_ln_g, ge_ln_b, w1T, ge_b1,
        w2qb, dotsb, at0, stag, phb, 0);
    k_softmax_reduce<<<32, 256, 0, stream>>>(dotsb, at0, stag);
    if (s < 3) {
      k_fused_mfma<<<dim3(16, NBK), 256, 0, stream>>>(
          vbuf, posb, sclb, gp_w, gp_b, ge_ln_g, ge_ln_b, w1T, ge_b1,
          w2qb, dotsb, at0, stag, phb, 1);
      k_upd<<<2, 256, 0, stream>>>(phb, w2T, ge_b2, Ub);
      k_gates<<<12, 256, 0, stream>>>(Ub, sf, wihB, whhB, gxh);
      k_slot<<<NBK, 256, 0, stream>>>(gxh, sf, gru_bih, gru_bhh, ns_g, ns_b,
                                      lnb16, posb, sclb, stag, phb, 1);
      k_q<<<2, 256, 0, stream>>>(lnb16, wqT, ge_b2, Qb, stag);
      k_w2q<<<4, 256, 0, stream>>>(Qb, w2B, w2qb);
    }
  }

  k_finalize<<<NBK, 256, 0, stream>>>(sf, at0, posb, sclb, stag, out);
}

// Round 10
// 564.143 us; speedup vs baseline: 1.8550x; 1.0123x over previous
//
#include <hip/hip_runtime.h>
#include <math.h>

#define NB 8
#define NN 1024
#define NK 8
#define ND 256
#define ND2 512
#define NBK 64
#define EPSA 1e-8f
#define LNEPS 1e-5f
#define GSTEP (2.0f/31.0f)

using short8 = __attribute__((ext_vector_type(8))) short;
using short4v = __attribute__((ext_vector_type(4))) short;
using floatx4 = __attribute__((ext_vector_type(4))) float;

__device__ __forceinline__ short f2bf(float f) {
  unsigned u = __builtin_bit_cast(unsigned, f);
  u += 0x7fffu + ((u >> 16) & 1u);
  return (short)(u >> 16);
}
__device__ __forceinline__ float bf2f(short s) {
  unsigned u = ((unsigned)(unsigned short)s) << 16;
  return __builtin_bit_cast(float, u);
}

// ---------------- weight conversions + small bias-fold vectors ----------------
// [0,131072) w1T[n][k]; [131072,196608) wkT; [196608,262144) wvT;
// [262144,458752) whhB direct; [458752,589824) w2B direct;
// [589824,590592) bx[j]=b2.wih_row_j; [590592,590848) vb[e]=wq_row_e.b2
__global__ __launch_bounds__(256) void k_cvt_all(
    const float* __restrict__ w1, const float* __restrict__ w2,
    const float* __restrict__ wk, const float* __restrict__ wv,
    const float* __restrict__ wih, const float* __restrict__ whh,
    const float* __restrict__ wq, const float* __restrict__ b2,
    short* __restrict__ w1T, short* __restrict__ wkT, short* __restrict__ wvT,
    short* __restrict__ whhB, short* __restrict__ w2B,
    float* __restrict__ bx, float* __restrict__ vb) {
  const int idx = blockIdx.x * 256 + threadIdx.x;
  if (idx < 131072) {
    const int n = idx >> 8, k = idx & 255;
    w1T[idx] = f2bf(w1[(size_t)k * 512 + n]);
  } else if (idx < 196608) {
    const int i = idx - 131072;
    const int n = i >> 8, k = i & 255;
    wkT[i] = f2bf(wk[(size_t)k * 256 + n]);
  } else if (idx < 262144) {
    const int i = idx - 196608;
    const int n = i >> 8, k = i & 255;
    wvT[i] = f2bf(wv[(size_t)k * 256 + n]);
  } else if (idx < 458752) {
    const int i = idx - 262144;
    whhB[i] = f2bf(whh[i]);
  } else if (idx < 589824) {
    const int i = idx - 458752;
    w2B[i] = f2bf(w2[i]);
  } else if (idx < 590592) {
    const int j = idx - 589824;
    float s = 0.f;
#pragma unroll 8
    for (int d = 0; d < 256; d++) s = fmaf(b2[d], wih[(size_t)j * 256 + d], s);
    bx[j] = s;
  } else if (idx < 590848) {
    const int e = idx - 590592;
    float s = 0.f;
#pragma unroll 8
    for (int d = 0; d < 256; d++) s = fmaf(wq[(size_t)e * 256 + d], b2[d], s);
    vb[e] = s;
  }
}

// ---------------- precompute WXT = wih @ w2^T (768x512), MQ = wq @ w2^T (256x512) ----------------
__global__ __launch_bounds__(256, 2) void k_mm(
    const float* __restrict__ wih, const float* __restrict__ wq,
    const short* __restrict__ w2B,
    short* __restrict__ WXT, short* __restrict__ MQ) {
  const int z = blockIdx.z;
  if (z == 1 && blockIdx.x >= 4) return;
  const float* __restrict__ A = z ? wq : wih;
  short* __restrict__ C = z ? MQ : WXT;
  __shared__ __align__(16) short As[64 * 264];
  const int row0 = blockIdx.x * 64;
  const int col0 = blockIdx.y * 128;
  const int t = threadIdx.x;
  const int wave = t >> 6, lane = t & 63, l15 = lane & 15, quad = lane >> 4;
  {
    const int r = t >> 2, sub = t & 3;
    const float* ar = A + (size_t)(row0 + r) * 256;
#pragma unroll
    for (int ii = 0; ii < 16; ii++) {
      const int d = sub * 4 + ii * 16;
      const float4 v = *(const float4*)(ar + d);
      short4v pk = {f2bf(v.x), f2bf(v.y), f2bf(v.z), f2bf(v.w)};
      *(short4v*)&As[r * 264 + d] = pk;
    }
  }
  __syncthreads();
  const short* wp = w2B + (size_t)(col0 + wave * 32 + l15) * 256 + quad * 8;
  floatx4 acc[4][2];
#pragma unroll
  for (int mt = 0; mt < 4; mt++)
#pragma unroll
    for (int nt = 0; nt < 2; nt++) acc[mt][nt] = (floatx4){0.f, 0.f, 0.f, 0.f};
#pragma unroll
  for (int kk = 0; kk < 8; kk++) {
    short8 af[4];
#pragma unroll
    for (int mt = 0; mt < 4; mt++)
      af[mt] = *(const short8*)&As[(mt * 16 + l15) * 264 + kk * 32 + quad * 8];
    short8 bf[2];
#pragma unroll
    for (int nt = 0; nt < 2; nt++)
      bf[nt] = *(const short8*)(wp + nt * 16 * 256 + kk * 32);
#pragma unroll
    for (int mt = 0; mt < 4; mt++)
#pragma unroll
      for (int nt = 0; nt < 2; nt++)
        acc[mt][nt] = __builtin_amdgcn_mfma_f32_16x16x32_bf16(af[mt], bf[nt], acc[mt][nt], 0, 0, 0);
  }
#pragma unroll
  for (int mt = 0; mt < 4; mt++)
#pragma unroll
    for (int nt = 0; nt < 2; nt++)
#pragma unroll
      for (int j = 0; j < 4; j++)
        C[(size_t)(row0 + mt * 16 + quad * 4 + j) * 512 + col0 + wave * 32 + nt * 16 + l15] =
            f2bf(acc[mt][nt][j]);
}

// ---------------- k/v projection via bf16 MFMA (LN stats inline) ----------------
__global__ __launch_bounds__(256, 2) void k_gemm_kv_mfma(
    const float* __restrict__ inp,
    const float* __restrict__ nig, const float* __restrict__ nib,
    const short* __restrict__ wkT, const short* __restrict__ wvT,
    float* __restrict__ kout, float* __restrict__ vout) {
  __shared__ __align__(16) short tln[64 * 264];
  const short* __restrict__ WT = blockIdx.z ? wvT : wkT;
  float* __restrict__ out = blockIdx.z ? vout : kout;
  const int row0 = blockIdx.x * 64;
  const int t = threadIdx.x;
  const int wave = t >> 6, lane = t & 63, l15 = lane & 15, quad = lane >> 4;
  {
    const int r = t >> 2, sub = t & 3;
    const float* xr = inp + (size_t)(row0 + r) * ND;
    float tv[64];
    float sum = 0.f, ssq = 0.f;
#pragma unroll
    for (int ii = 0; ii < 16; ii++) {
      const int d = sub * 4 + ii * 16;
      const float4 xv = *(const float4*)(xr + d);
      tv[ii * 4 + 0] = xv.x; sum += xv.x; ssq += xv.x * xv.x;
      tv[ii * 4 + 1] = xv.y; sum += xv.y; ssq += xv.y * xv.y;
      tv[ii * 4 + 2] = xv.z; sum += xv.z; ssq += xv.z * xv.z;
      tv[ii * 4 + 3] = xv.w; sum += xv.w; ssq += xv.w * xv.w;
    }
    sum += __shfl_xor(sum, 1); ssq += __shfl_xor(ssq, 1);
    sum += __shfl_xor(sum, 2); ssq += __shfl_xor(ssq, 2);
    const float mean = sum * (1.0f / ND);
    const float var = ssq * (1.0f / ND) - mean * mean;
    const float rstd = rsqrtf(var + LNEPS);
#pragma unroll
    for (int ii = 0; ii < 16; ii++) {
      const int d = sub * 4 + ii * 16;
      const float4 gg = *(const float4*)(nig + d);
      const float4 bb = *(const float4*)(nib + d);
      short4v pk;
      pk.x = f2bf((tv[ii * 4 + 0] - mean) * rstd * gg.x + bb.x);
      pk.y = f2bf((tv[ii * 4 + 1] - mean) * rstd * gg.y + bb.y);
      pk.z = f2bf((tv[ii * 4 + 2] - mean) * rstd * gg.z + bb.z);
      pk.w = f2bf((tv[ii * 4 + 3] - mean) * rstd * gg.w + bb.w);
      *(short4v*)&tln[r * 264 + d] = pk;
    }
  }
  __syncthreads();
  floatx4 acc[4][4];
#pragma unroll
  for (int mt = 0; mt < 4; mt++)
#pragma unroll
    for (int nt = 0; nt < 4; nt++) acc[mt][nt] = (floatx4){0.f, 0.f, 0.f, 0.f};
  const short* wp = WT + ((size_t)(wave * 64 + l15)) * 256 + quad * 8;
#pragma unroll
  for (int kk = 0; kk < 8; kk++) {
    short8 af[4];
#pragma unroll
    for (int mt = 0; mt < 4; mt++)
      af[mt] = *(const short8*)&tln[(mt * 16 + l15) * 264 + kk * 32 + quad * 8];
    short8 bf[4];
#pragma unroll
    for (int nt = 0; nt < 4; nt++)
      bf[nt] = *(const short8*)(wp + nt * 16 * 256 + kk * 32);
#pragma unroll
    for (int mt = 0; mt < 4; mt++)
#pragma unroll
      for (int nt = 0; nt < 4; nt++)
        acc[mt][nt] = __builtin_amdgcn_mfma_f32_16x16x32_bf16(af[mt], bf[nt], acc[mt][nt], 0, 0, 0);
  }
#pragma unroll
  for (int mt = 0; mt < 4; mt++)
#pragma unroll
    for (int nt = 0; nt < 4; nt++)
#pragma unroll
      for (int j = 0; j < 4; j++)
        out[(size_t)(row0 + mt * 16 + quad * 4 + j) * ND + wave * 64 + nt * 16 + l15] = acc[mt][nt][j];
}

// ---------------- fused grid_enc pass: GEMM1 only (W2 folded out) ----------------
#define LDA 264

__global__ __launch_bounds__(256, 2) void k_fused_mfma(
    const float* __restrict__ kv,
    const float* __restrict__ pos, const float* __restrict__ scl,
    const float* __restrict__ gpw, const float* __restrict__ gpb,
    const float* __restrict__ lng, const float* __restrict__ lnb,
    const short* __restrict__ w1T, const float* __restrict__ b1,
    const float* __restrict__ w2q, float* __restrict__ dots,
    const float* __restrict__ attn0, const float* __restrict__ stage,
    float* __restrict__ ph, const int mode) {
  __shared__ __align__(16) short tln[64 * LDA];  // 33 KB; dred aliases after barrier

  const int bk = blockIdx.y;
  const int n0 = blockIdx.x * 64;
  const int b = bk >> 3;
  const int t = threadIdx.x;
  const int wave = t >> 6;
  const int lane = t & 63;
  const int l15 = lane & 15;
  const int quad = lane >> 4;

  // ---- Phase A: tln = LN(kv + rel_enc) -> bf16 LDS (64 rows, 4 thr/row) ----
  {
    const float p0 = pos[bk * 2 + 0], p1 = pos[bk * 2 + 1];
    const float s0i = 1.0f / (scl[bk * 2 + 0] * 5.0f);
    const float s1i = 1.0f / (scl[bk * 2 + 1] * 5.0f);
    const int r = t >> 2;
    const int sub = t & 3;
    const int n = n0 + r;
    const float gx = -1.0f + GSTEP * (float)(n >> 5);
    const float gy = -1.0f + GSTEP * (float)(n & 31);
    const float rg0 = (gx - p0) * s0i;
    const float rg1 = (gy - p1) * s1i;
    const float* kvrow = kv + (size_t)(b * NN + n) * ND;
    float tv[64];
    float sum = 0.f, ssq = 0.f;
#pragma unroll
    for (int ii = 0; ii < 16; ii++) {
      const int d = sub * 4 + ii * 16;
      const float4 kv4 = *(const float4*)(kvrow + d);
      const float4 wa = *(const float4*)(gpw + d);
      const float4 wb = *(const float4*)(gpw + ND + d);
      const float4 pb = *(const float4*)(gpb + d);
      float v0 = kv4.x + rg0 * wa.x + rg1 * wb.x + pb.x;
      float v1 = kv4.y + rg0 * wa.y + rg1 * wb.y + pb.y;
      float v2 = kv4.z + rg0 * wa.z + rg1 * wb.z + pb.z;
      float v3 = kv4.w + rg0 * wa.w + rg1 * wb.w + pb.w;
      tv[ii * 4 + 0] = v0; sum += v0; ssq += v0 * v0;
      tv[ii * 4 + 1] = v1; sum += v1; ssq += v1 * v1;
      tv[ii * 4 + 2] = v2; sum += v2; ssq += v2 * v2;
      tv[ii * 4 + 3] = v3; sum += v3; ssq += v3 * v3;
    }
    sum += __shfl_xor(sum, 1); ssq += __shfl_xor(ssq, 1);
    sum += __shfl_xor(sum, 2); ssq += __shfl_xor(ssq, 2);
    const float mean = sum * (1.0f / ND);
    const float var = ssq * (1.0f / ND) - mean * mean;
    const float rstd = rsqrtf(var + LNEPS);
#pragma unroll
    for (int ii = 0; ii < 16; ii++) {
      const int d = sub * 4 + ii * 16;
      const float4 gg = *(const float4*)(lng + d);
      const float4 bb = *(const float4*)(lnb + d);
      short4v pk;
      pk.x = f2bf((tv[ii * 4 + 0] - mean) * rstd * gg.x + bb.x);
      pk.y = f2bf((tv[ii * 4 + 1] - mean) * rstd * gg.y + bb.y);
      pk.z = f2bf((tv[ii * 4 + 2] - mean) * rstd * gg.z + bb.z);
      pk.w = f2bf((tv[ii * 4 + 3] - mean) * rstd * gg.w + bb.w);
      *(short4v*)&tln[r * LDA + d] = pk;
    }
  }
  __syncthreads();

  // ---- GEMM1: h1 = tln @ W1T^T (relu+bias in epilogue). Wave owns 128 cols. ----
  floatx4 acc1[4][8];
#pragma unroll
  for (int mt = 0; mt < 4; mt++)
#pragma unroll
    for (int nt = 0; nt < 8; nt++) acc1[mt][nt] = (floatx4){0.f, 0.f, 0.f, 0.f};

  const short* w1p = w1T + ((size_t)(wave * 128 + l15)) * 256 + quad * 8;
#pragma unroll
  for (int kk = 0; kk < 8; kk++) {
    short8 af[4];
#pragma unroll
    for (int mt = 0; mt < 4; mt++)
      af[mt] = *(const short8*)&tln[(mt * 16 + l15) * LDA + kk * 32 + quad * 8];
    short8 bf[8];
#pragma unroll
    for (int nt = 0; nt < 8; nt++)
      bf[nt] = *(const short8*)(w1p + nt * 16 * 256 + kk * 32);
#pragma unroll
    for (int mt = 0; mt < 4; mt++)
#pragma unroll
      for (int nt = 0; nt < 8; nt++)
        acc1[mt][nt] = __builtin_amdgcn_mfma_f32_16x16x32_bf16(af[mt], bf[nt], acc1[mt][nt], 0, 0, 0);
  }

  float b1v[8];
#pragma unroll
  for (int nt = 0; nt < 8; nt++) b1v[nt] = b1[wave * 128 + nt * 16 + l15];

  if (mode == 0) {
    float w2qv[8];
#pragma unroll
    for (int nt = 0; nt < 8; nt++) w2qv[nt] = w2q[bk * 512 + wave * 128 + nt * 16 + l15];
    const float qb2 = stage[bk * 8 + 5];
    __syncthreads();  // all tln reads done; alias as dred
    float* dred = (float*)tln;
#pragma unroll
    for (int mt = 0; mt < 4; mt++)
#pragma unroll
      for (int j = 0; j < 4; j++) {
        float p = 0.f;
#pragma unroll
        for (int nt = 0; nt < 8; nt++)
          p = fmaf(fmaxf(acc1[mt][nt][j] + b1v[nt], 0.f), w2qv[nt], p);
        p += __shfl_xor(p, 1); p += __shfl_xor(p, 2);
        p += __shfl_xor(p, 4); p += __shfl_xor(p, 8);
        if (l15 == 0) dred[wave * 64 + mt * 16 + quad * 4 + j] = p;
      }
    __syncthreads();
    if (t < 64) {
      const float s = dred[t] + dred[64 + t] + dred[128 + t] + dred[192 + t];
      dots[bk * NN + n0 + t] = (s + qb2) * 0.0625f;
    }
  } else {
    const float dn = 1.0f / (stage[bk * 8 + 0] + (float)NN * EPSA);
    float aw[4][4];
#pragma unroll
    for (int mt = 0; mt < 4; mt++)
#pragma unroll
      for (int j = 0; j < 4; j++)
        aw[mt][j] = (attn0[bk * NN + n0 + mt * 16 + quad * 4 + j] + EPSA) * dn;
#pragma unroll
    for (int nt = 0; nt < 8; nt++) {
      float cs = 0.f;
#pragma unroll
      for (int mt = 0; mt < 4; mt++)
#pragma unroll
        for (int j = 0; j < 4; j++)
          cs = fmaf(aw[mt][j], fmaxf(acc1[mt][nt][j] + b1v[nt], 0.f), cs);
      cs += __shfl_xor(cs, 16); cs += __shfl_xor(cs, 32);
      if (quad == 0) atomicAdd(ph + bk * 512 + wave * 128 + nt * 16 + l15, cs);
    }
  }
}

// ---------------- softmax over K + one-pass moment sums -> stage ----------------
__global__ __launch_bounds__(256) void k_softmax_reduce(
    const float* __restrict__ dots, float* __restrict__ attn0,
    float* __restrict__ stage) {
  const int t = threadIdx.x;
  const int idx = blockIdx.x * 256 + t;
  const int b = idx >> 10, n = idx & 1023;
  const int lane = t & 63, wave = t >> 6;
  float vals[NK];
  float mx = -1e30f;
#pragma unroll
  for (int k = 0; k < NK; k++) {
    vals[k] = dots[(size_t)(b * NK + k) * NN + n];
    mx = fmaxf(mx, vals[k]);
  }
  float s = 0.f;
#pragma unroll
  for (int k = 0; k < NK; k++) { vals[k] = expf(vals[k] - mx); s += vals[k]; }
  const float inv = 1.0f / s;
  const float gx = -1.0f + GSTEP * (float)(n >> 5);
  const float gy = -1.0f + GSTEP * (float)(n & 31);
  const float gx2 = gx * gx, gy2 = gy * gy;
  float sk[NK][5];
#pragma unroll
  for (int k = 0; k < NK; k++) {
    const float a = vals[k] * inv;
    attn0[(size_t)(b * NK + k) * NN + n] = a;
    const float w = a + EPSA;
    sk[k][0] = a;
    sk[k][1] = a * gx;
    sk[k][2] = a * gy;
    sk[k][3] = w * gx2;
    sk[k][4] = w * gy2;
  }
#pragma unroll
  for (int m = 32; m >= 1; m >>= 1)
#pragma unroll
    for (int k = 0; k < NK; k++)
#pragma unroll
      for (int c = 0; c < 5; c++)
        sk[k][c] += __shfl_xor(sk[k][c], m);
  __shared__ float red[4][40];
  if (lane == 0) {
#pragma unroll
    for (int k = 0; k < NK; k++)
#pragma unroll
      for (int c = 0; c < 5; c++)
        red[wave][k * 5 + c] = sk[k][c];
  }
  __syncthreads();
  if (t < 40) {
    const float tot = red[0][t] + red[1][t] + red[2][t] + red[3][t];
    const int k = t / 5, c = t % 5;
    atomicAdd(&stage[(b * NK + k) * 8 + c], tot);
  }
}

// ---------------- k_gatesC: gxh = [ph@WXT + bx | slots@whh^T] -> bf16 ----------------
__global__ __launch_bounds__(256) void k_gatesC(
    const float* __restrict__ ph, const float* __restrict__ sf,
    const short* __restrict__ WXT, const short* __restrict__ whhB,
    const float* __restrict__ bx, short* __restrict__ gxh) {
  __shared__ __align__(16) short A[64 * 264];
  const int c = blockIdx.x;          // 0..11
  const int isX = (c < 6) ? 1 : 0;
  const int jb = (isX ? c : c - 6) * 128;
  const int t = threadIdx.x;
  const int wave = t >> 6, lane = t & 63, l15 = lane & 15, quad = lane >> 4;
  const int r = t >> 2, sub = t & 3;
  floatx4 acc[4][2];
#pragma unroll
  for (int mt = 0; mt < 4; mt++)
#pragma unroll
    for (int nt = 0; nt < 2; nt++) acc[mt][nt] = (floatx4){0.f, 0.f, 0.f, 0.f};

  if (isX) {
#pragma unroll
    for (int half = 0; half < 2; half++) {
      if (half > 0) __syncthreads();
#pragma unroll
      for (int ii = 0; ii < 16; ii++) {
        const int d = sub * 4 + ii * 16;
        const float4 v = *(const float4*)(ph + r * 512 + half * 256 + d);
        short4v pk = {f2bf(v.x), f2bf(v.y), f2bf(v.z), f2bf(v.w)};
        *(short4v*)&A[r * 264 + d] = pk;
      }
      __syncthreads();
      const short* wp = WXT + (size_t)(jb + wave * 32 + l15) * 512 + half * 256 + quad * 8;
#pragma unroll
      for (int kk = 0; kk < 8; kk++) {
        short8 af[4];
#pragma unroll
        for (int mt = 0; mt < 4; mt++)
          af[mt] = *(const short8*)&A[(mt * 16 + l15) * 264 + kk * 32 + quad * 8];
        short8 bf[2];
#pragma unroll
        for (int nt = 0; nt < 2; nt++)
          bf[nt] = *(const short8*)(wp + nt * 16 * 512 + kk * 32);
#pragma unroll
        for (int mt = 0; mt < 4; mt++)
#pragma unroll
          for (int nt = 0; nt < 2; nt++)
            acc[mt][nt] = __builtin_amdgcn_mfma_f32_16x16x32_bf16(af[mt], bf[nt], acc[mt][nt], 0, 0, 0);
      }
    }
#pragma unroll
    for (int nt = 0; nt < 2; nt++) {
      const int col = jb + wave * 32 + nt * 16 + l15;
      const float bxv = bx[col];
#pragma unroll
      for (int mt = 0; mt < 4; mt++)
#pragma unroll
        for (int j = 0; j < 4; j++)
          gxh[(mt * 16 + quad * 4 + j) * 1536 + col] = f2bf(acc[mt][nt][j] + bxv);
    }
  } else {
#pragma unroll
    for (int ii = 0; ii < 16; ii++) {
      const int d = sub * 4 + ii * 16;
      const float4 v = *(const float4*)(sf + r * 260 + d);
      short4v pk = {f2bf(v.x), f2bf(v.y), f2bf(v.z), f2bf(v.w)};
      *(short4v*)&A[r * 264 + d] = pk;
    }
    __syncthreads();
    const short* wp = whhB + (size_t)(jb + wave * 32 + l15) * 256 + quad * 8;
#pragma unroll
    for (int kk = 0; kk < 8; kk++) {
      short8 af[4];
#pragma unroll
      for (int mt = 0; mt < 4; mt++)
        af[mt] = *(const short8*)&A[(mt * 16 + l15) * 264 + kk * 32 + quad * 8];
      short8 bf[2];
#pragma unroll
      for (int nt = 0; nt < 2; nt++)
        bf[nt] = *(const short8*)(wp + nt * 16 * 256 + kk * 32);
#pragma unroll
      for (int mt = 0; mt < 4; mt++)
#pragma unroll
        for (int nt = 0; nt < 2; nt++)
          acc[mt][nt] = __builtin_amdgcn_mfma_f32_16x16x32_bf16(af[mt], bf[nt], acc[mt][nt], 0, 0, 0);
    }
#pragma unroll
    for (int mt = 0; mt < 4; mt++)
#pragma unroll
      for (int nt = 0; nt < 2; nt++)
#pragma unroll
        for (int j = 0; j < 4; j++)
          gxh[(mt * 16 + quad * 4 + j) * 1536 + 768 + jb + wave * 32 + nt * 16 + l15] =
              f2bf(acc[mt][nt][j]);
  }
}

// ---------------- k_slotW: GRU elementwise + LN + pos/scl + w2q + qb2 + zeroing ----------------
__global__ __launch_bounds__(256) void k_slotW(
    const short* __restrict__ gxh, float* __restrict__ sf,
    const float* __restrict__ cond,
    const float* __restrict__ bih, const float* __restrict__ bhh,
    const float* __restrict__ nsg, const float* __restrict__ nsb,
    const short* __restrict__ MQ, const float* __restrict__ vb,
    float* __restrict__ w2q, float* __restrict__ pos, float* __restrict__ scl,
    float* __restrict__ stage, float* __restrict__ ph, const int mode) {
  const int bk = blockIdx.x, t = threadIdx.x;
  __shared__ float lnvS[256];
  __shared__ float red[8];
  const int wv = t >> 6;
  float ns;
  if (mode) {
    const float h = sf[bk * 260 + t];
    const float x0 = bf2f(gxh[bk * 1536 + t]);
    const float x1 = bf2f(gxh[bk * 1536 + 256 + t]);
    const float x2 = bf2f(gxh[bk * 1536 + 512 + t]);
    const float h0 = bf2f(gxh[bk * 1536 + 768 + t]);
    const float h1v = bf2f(gxh[bk * 1536 + 1024 + t]);
    const float h2 = bf2f(gxh[bk * 1536 + 1280 + t]);
    const float r = 1.0f / (1.0f + expf(-(x0 + bih[t] + h0 + bhh[t])));
    const float z = 1.0f / (1.0f + expf(-(x1 + bih[256 + t] + h1v + bhh[256 + t])));
    const float nw = tanhf(x2 + bih[512 + t] + r * (h2 + bhh[512 + t]));
    ns = (1.0f - z) * nw + z * h;
    sf[bk * 260 + t] = ns;
  } else {
    ns = cond[bk * 260 + t];
    sf[bk * 260 + t] = ns;
    if (t < 4) sf[bk * 260 + 256 + t] = cond[bk * 260 + 256 + t];
  }
  float s2 = ns, ss = ns * ns;
#pragma unroll
  for (int m = 32; m >= 1; m >>= 1) { s2 += __shfl_xor(s2, m); ss += __shfl_xor(ss, m); }
  if ((t & 63) == 0) { red[wv] = s2; red[4 + wv] = ss; }
  __syncthreads();
  const float S = red[0] + red[1] + red[2] + red[3];
  const float SS = red[4] + red[5] + red[6] + red[7];
  const float mean = S * (1.0f / ND);
  const float var = SS * (1.0f / ND) - mean * mean;
  const float rstd = rsqrtf(var + LNEPS);
  const float lnv = (ns - mean) * rstd * nsg[t] + nsb[t];
  lnvS[t] = lnv;
  if (mode) {
    if (t == 0) {
      const float Sa = stage[bk * 8 + 0];
      const float G0 = stage[bk * 8 + 1];
      const float G1 = stage[bk * 8 + 2];
      const float Q0 = stage[bk * 8 + 3];
      const float Q1 = stage[bk * 8 + 4];
      const float W = Sa + (float)NN * EPSA;
      const float sc0 = sqrtf(fmaxf(Q0 - 2.0f * G0 * G0 + G0 * G0 * W, 0.f));
      const float sc1 = sqrtf(fmaxf(Q1 - 2.0f * G1 * G1 + G1 * G1 * W, 0.f));
      const float sc0c = fminf(fmaxf(sc0, 1e-3f), 2.0f);
      const float sc1c = fminf(fmaxf(sc1, 1e-3f), 2.0f);
      sf[bk * 260 + 256] = G0;
      sf[bk * 260 + 257] = G1;
      sf[bk * 260 + 258] = sc0c;
      sf[bk * 260 + 259] = sc1c;
      pos[bk * 2 + 0] = fminf(fmaxf(G0, -1.0f), 1.0f);
      pos[bk * 2 + 1] = fminf(fmaxf(G1, -1.0f), 1.0f);
      scl[bk * 2 + 0] = sc0c;
      scl[bk * 2 + 1] = sc1c;
    }
  } else {
    if (t < 2) {
      const float p = cond[bk * 260 + 256 + t];
      pos[bk * 2 + t] = fminf(fmaxf(p, -1.0f), 1.0f);
      const float sc = cond[bk * 260 + 258 + t];
      scl[bk * 2 + t] = fminf(fmaxf(sc, 1e-3f), 2.0f);
    }
  }
  __syncthreads();  // lnvS ready; stage moment reads done
  if (t < 5) stage[bk * 8 + t] = 0.f;
  ph[bk * 512 + t] = 0.f;
  ph[bk * 512 + 256 + t] = 0.f;
  // w2q = lnv @ MQ  (two output cols per thread, coalesced)
  float w0 = 0.f, w1v = 0.f;
#pragma unroll 8
  for (int e = 0; e < ND; e++) {
    const float lv = lnvS[e];
    w0 = fmaf(lv, bf2f(MQ[e * 512 + t]), w0);
    w1v = fmaf(lv, bf2f(MQ[e * 512 + 256 + t]), w1v);
  }
  w2q[bk * 512 + t] = w0;
  w2q[bk * 512 + 256 + t] = w1v;
  // qb2 = lnv . vb
  float qd = lnvS[t] * vb[t];
#pragma unroll
  for (int m = 32; m >= 1; m >>= 1) qd += __shfl_xor(qd, m);
  __syncthreads();  // red free for reuse
  if ((t & 63) == 0) red[wv] = qd;
  __syncthreads();
  if (t == 0) stage[bk * 8 + 5] = red[0] + red[1] + red[2] + red[3];
}

// ---------------- finalize ----------------
__global__ __launch_bounds__(256) void k_finalize(
    const float* __restrict__ sf, const float* __restrict__ attn0,
    const float* __restrict__ pos, const float* __restrict__ scl,
    const float* __restrict__ stage, float* __restrict__ out) {
  const int bk = blockIdx.x, t = threadIdx.x;
  out[bk * 260 + t] = sf[bk * 260 + t];
  if (t == 0) {
    const float Sa = stage[bk * 8 + 0];
    const float G0 = stage[bk * 8 + 1];
    const float G1 = stage[bk * 8 + 2];
    const float Q0 = stage[bk * 8 + 3];
    const float Q1 = stage[bk * 8 + 4];
    const float W = Sa + (float)NN * EPSA;
    const float sc0 = sqrtf(fmaxf(Q0 - 2.0f * G0 * G0 + G0 * G0 * W, 0.f));
    const float sc1 = sqrtf(fmaxf(Q1 - 2.0f * G1 * G1 + G1 * G1 * W, 0.f));
    out[bk * 260 + 256] = G0;
    out[bk * 260 + 257] = G1;
    out[bk * 260 + 258] = fminf(fmaxf(sc0, 1e-3f), 2.0f);
    out[bk * 260 + 259] = fminf(fmaxf(sc1, 1e-3f), 2.0f);
  }
  const float p0 = pos[bk * 2 + 0], p1 = pos[bk * 2 + 1];
  const float s0 = scl[bk * 2 + 0] * 5.0f, s1 = scl[bk * 2 + 1] * 5.0f;
#pragma unroll
  for (int i = 0; i < 4; i++) {
    const int n = t + 256 * i;
    out[16640 + bk * NN + n] = attn0[(size_t)bk * NN + n];
    const float gx = -1.0f + GSTEP * (float)(n >> 5);
    const float gy = -1.0f + GSTEP * (float)(n & 31);
    float2 v;
    v.x = (gx - p0) / s0;
    v.y = (gy - p1) / s1;
    *(float2*)(out + 16640 + 65536 + ((size_t)bk * NN + n) * 2) = v;
  }
}

extern "C" void kernel_launch(void* const* d_in, const int* in_sizes, int n_in,
                              void* d_out, int out_size, void* d_ws, size_t ws_size,
                              hipStream_t stream) {
  const float* inputs   = (const float*)d_in[0];
  const float* cond     = (const float*)d_in[1];
  const float* ni_g     = (const float*)d_in[2];
  const float* ni_b     = (const float*)d_in[3];
  const float* ns_g     = (const float*)d_in[4];
  const float* ns_b     = (const float*)d_in[5];
  const float* wq       = (const float*)d_in[6];
  const float* wk       = (const float*)d_in[7];
  const float* wv       = (const float*)d_in[8];
  const float* gp_w     = (const float*)d_in[9];
  const float* gp_b     = (const float*)d_in[10];
  const float* ge_ln_g  = (const float*)d_in[11];
  const float* ge_ln_b  = (const float*)d_in[12];
  const float* ge_w1    = (const float*)d_in[13];
  const float* ge_b1    = (const float*)d_in[14];
  const float* ge_w2    = (const float*)d_in[15];
  const float* ge_b2    = (const float*)d_in[16];
  const float* gru_wih  = (const float*)d_in[17];
  const float* gru_whh  = (const float*)d_in[18];
  const float* gru_bih  = (const float*)d_in[19];
  const float* gru_bhh  = (const float*)d_in[20];

  float* ws   = (float*)d_ws;
  float* kbuf = ws;                  // 8*1024*256
  float* vbuf = kbuf + 2097152;      // 8*1024*256
  float* sf   = vbuf + 2097152;      // 64*260
  float* w2qb = sf + 16640;          // 64*512
  float* posb = w2qb + 32768;        // 64*2 (padded)
  float* sclb = posb + 128;          // 64*2 (padded)
  float* dotsb = sclb + 128;         // 64*1024
  float* at0  = dotsb + 65536;       // 64*1024
  float* phb  = at0 + 65536;         // 64*512
  float* stag = phb + 32768;         // 64*8
  float* bxb  = stag + 512;          // 768
  float* vbb  = bxb + 768;           // 256
  short* gxh  = (short*)(vbb + 256);      // 64*1536 bf16
  short* w1T  = gxh + 98304;              // 512*256 bf16
  short* wkT  = w1T + 131072;             // 256*256 bf16
  short* wvT  = wkT + 65536;              // 256*256 bf16
  short* whhB = wvT + 65536;              // 768*256 bf16
  short* w2B  = whhB + 196608;            // 512*256 bf16
  short* WXT  = w2B + 131072;             // 768*512 bf16
  short* MQ   = WXT + 393216;             // 256*512 bf16

  float* out = (float*)d_out;

  k_cvt_all<<<2308, 256, 0, stream>>>(ge_w1, ge_w2, wk, wv, gru_wih, gru_whh, wq,
                                      ge_b2, w1T, wkT, wvT, whhB, w2B, bxb, vbb);
  k_mm<<<dim3(12, 4, 2), 256, 0, stream>>>(gru_wih, wq, w2B, WXT, MQ);
  k_gemm_kv_mfma<<<dim3(128, 1, 2), 256, 0, stream>>>(inputs, ni_g, ni_b,
                                                      wkT, wvT, kbuf, vbuf);
  k_slotW<<<NBK, 256, 0, stream>>>(gxh, sf, cond, gru_bih, gru_bhh, ns_g, ns_b,
                                   MQ, vbb, w2qb, posb, sclb, stag, phb, 0);

  for (int s = 0; s < 4; s++) {
    k_fused_mfma<<<dim3(16, NBK), 256, 0, stream>>>(
        kbuf, posb, sclb, gp_w, gp_b, ge_ln_g, ge_ln_b, w1T, ge_b1,
        w2qb, dotsb, at0, stag, phb, 0);
    k_softmax_reduce<<<32, 256, 0, stream>>>(dotsb, at0, stag);
    if (s < 3) {
      k_fused_mfma<<<dim3(16, NBK), 256, 0, stream>>>(
          vbuf, posb, sclb, gp_w, gp_b, ge_ln_g, ge_ln_b, w1T, ge_b1,
          w2qb, dotsb, at0, stag, phb, 1);
      k_gatesC<<<12, 256, 0, stream>>>(phb, sf, WXT, whhB, bxb, gxh);
      k_slotW<<<NBK, 256, 0, stream>>>(gxh, sf, cond, gru_bih, gru_bhh, ns_g, ns_b,
                                       MQ, vbb, w2qb, posb, sclb, stag, phb, 1);
    }
  }

  k_finalize<<<NBK, 256, 0, stream>>>(sf, at0, posb, sclb, stag, out);
}